// Round 4
// baseline (436.666 us; speedup 1.0000x reference)
//
#include <hip/hip_runtime.h>
#include <stdint.h>

#define B_ 4
#define S_ 2048
#define D_ 1024
#define H_ 16
#define DH_ 64
#define MROWS (B_*S_)   // 8192

typedef unsigned short ushortT;
typedef __attribute__((ext_vector_type(8))) short bf16x8;
typedef __attribute__((ext_vector_type(4))) float f32x4;

#define FLAG_BF16 1u
#define FLAG_F32  2u

__device__ __forceinline__ float b2f(ushortT u) {
  union { unsigned int i; float f; } v; v.i = ((unsigned int)u) << 16; return v.f;
}
__device__ __forceinline__ ushortT f2b(float f) {
  union { float f; unsigned int i; } v; v.f = f;
  unsigned int r = v.i + 0x7fffu + ((v.i >> 16) & 1u);
  return (ushortT)(r >> 16);
}

// scalar load -> float
__device__ __forceinline__ float loadf(const ushortT* p) { return b2f(*p); }
__device__ __forceinline__ float loadf(const float* p)   { return *p; }
// scalar -> bf16 bits (as uint)
__device__ __forceinline__ unsigned int tob(ushortT u) { return u; }
__device__ __forceinline__ unsigned int tob(float f)   { return f2b(f); }

// 8-wide load -> 8 bf16 ushorts (bf16: pure copy, no VALU)
__device__ __forceinline__ void load8b(const ushortT* p, ushortT* u) {
  *(uint4*)u = *(const uint4*)p;
}
__device__ __forceinline__ void load8b(const float* p, ushortT* u) {
  float4 a = ((const float4*)p)[0], b = ((const float4*)p)[1];
  u[0] = f2b(a.x); u[1] = f2b(a.y); u[2] = f2b(a.z); u[3] = f2b(a.w);
  u[4] = f2b(b.x); u[5] = f2b(b.y); u[6] = f2b(b.z); u[7] = f2b(b.w);
}
template <typename T>
__device__ __forceinline__ void load16b(const T* p, ushortT* u) {
  load8b(p, u); load8b(p + 8, u + 8);
}

// dtype-generic store
__device__ __forceinline__ void storef(ushortT* p, float v) { *p = f2b(v); }
__device__ __forceinline__ void storef(float* p, float v)   { *p = v; }

// async global->LDS, 16 bytes per lane (dest = uniform base + lane*16)
__device__ __forceinline__ void gload16(const ushortT* g, ushortT* l) {
  __builtin_amdgcn_global_load_lds(
      (const __attribute__((address_space(1))) void*)g,
      (__attribute__((address_space(3))) void*)l, 16, 0, 0);
}

// ---------------- dtype probe ------------------------------------------------
__global__ void detect_dtype(const unsigned int* __restrict__ xw,
                             unsigned int* __restrict__ flag) {
  int lane = threadIdx.x;
  int cnt = 0;
  for (int i = lane; i < 2048; i += 64) {
    unsigned int e = (xw[i] >> 7) & 0xFFu;
    cnt += (e >= 0x68u && e <= 0x8Au) ? 1 : 0;
  }
#pragma unroll
  for (int off = 32; off; off >>= 1) cnt += __shfl_down(cnt, off);
  if (lane == 0) *flag = (cnt > 1024) ? FLAG_BF16 : FLAG_F32;
}

// ---------------- x -> bf16 one-time convert (f32 pipeline only) -------------
__global__ __launch_bounds__(256) void cvt_x_f32(
    const float* __restrict__ x, ushortT* __restrict__ xb,
    const unsigned int* __restrict__ flag) {
  if (*flag != FLAG_F32) return;
  const int total = MROWS * D_ / 8;  // 8-elem chunks
  for (int i = blockIdx.x * 256 + threadIdx.x; i < total; i += gridDim.x * 256) {
    float4 a = ((const float4*)x)[2 * i], b = ((const float4*)x)[2 * i + 1];
    ushortT u[8];
    u[0] = f2b(a.x); u[1] = f2b(a.y); u[2] = f2b(a.z); u[3] = f2b(a.w);
    u[4] = f2b(b.x); u[5] = f2b(b.y); u[6] = f2b(b.z); u[7] = f2b(b.w);
    ((uint4*)xb)[i] = *(uint4*)u;
  }
}

// ---------------- MFMA GEMM body: C[M,N] = A[M,K] @ B[K,N] + bias ------------
// A is ALWAYS bf16 in global. Staged via global_load_lds_dwordx4 into linear
// [row][32] LDS. B (weights, native dtype) reg-staged transposed, prefetched
// one K-step ahead. 128x128 tile, BK=32, 256 threads (2x2 waves of 64x64).
// LDS is passed in from the wrapper so all template instantiations inside one
// kernel SHARE the allocation (separate static __shared__ per instantiation
// tripled LDS_Block_Size to 55 KB -> 2 blocks/CU, occupancy-starved).
#define BK 32
#define BSTRIDE 40
#define GEMM_LDS (128 * BK + 128 * BSTRIDE)   // 9216 ushorts = 18432 B

template <typename TB, typename TOUT>
__device__ __forceinline__ void gemm_body(
    const ushortT* __restrict__ A, const TB* __restrict__ Bm,
    const TB* __restrict__ bias, TOUT* __restrict__ C, ushortT* smem)
{
  const int K = 1024, N = 1024;
  ushortT* As = smem;              // 128*BK, linear (global_load_lds dest)
  ushortT* Bs = smem + 128 * BK;   // 128*BSTRIDE, padded
  int m0 = blockIdx.x * 128;
  int n0 = blockIdx.y * 128;
  int t = threadIdx.x;
  int lane = t & 63;
  int w = t >> 6;
  int wm = w >> 1, wn = w & 1;

  f32x4 acc[4][4] = {};

  // A: per-lane global src; wave-uniform LDS dest
  const ushortT* a_src0 = A + (size_t)(m0 + (t >> 2)) * K + (t & 3) * 8;
  const ushortT* a_src1 = a_src0 + (size_t)64 * K;
  ushortT* a_dst0 = &As[(16 * w) * BK];
  ushortT* a_dst1 = &As[(64 + 16 * w) * BK];

  // B: thread covers col cB, rows r0..r0+15 of each K-slab
  int cB = t & 127, r0 = (t >> 7) * 16;
  const TB* Bp0 = Bm + (size_t)r0 * N + n0 + cB;

  // prefetch B regs for kt=0
  TB breg[16];
#pragma unroll
  for (int j = 0; j < 16; ++j) breg[j] = Bp0[(size_t)j * N];

  for (int kt = 0; kt < K; kt += BK) {
    // stage A (async DMA, no VALU)
    gload16(a_src0 + kt, a_dst0);
    gload16(a_src1 + kt, a_dst1);
    // stage B from prefetched regs (transposed pack)
    {
      unsigned int* bd = (unsigned int*)&Bs[cB * BSTRIDE + r0];
#pragma unroll
      for (int j = 0; j < 8; ++j) {
        unsigned int lo = tob(breg[2 * j]);
        unsigned int hi = tob(breg[2 * j + 1]);
        bd[j] = lo | (hi << 16);
      }
    }
    __syncthreads();  // drains vmcnt (gll) + lgkm (ds_write)

    // prefetch next B tile (latency hides under MFMAs below)
    if (kt + BK < K) {
      const TB* bp = Bp0 + (size_t)(kt + BK) * N;
#pragma unroll
      for (int j = 0; j < 16; ++j) breg[j] = bp[(size_t)j * N];
    }

    int kq = (lane >> 4) * 8;
    int lm = lane & 15;
    bf16x8 af[4], bf[4];
#pragma unroll
    for (int mi = 0; mi < 4; ++mi)
      af[mi] = *(const bf16x8*)&As[(wm * 64 + mi * 16 + lm) * BK + kq];
#pragma unroll
    for (int ni = 0; ni < 4; ++ni)
      bf[ni] = *(const bf16x8*)&Bs[(wn * 64 + ni * 16 + lm) * BSTRIDE + kq];
#pragma unroll
    for (int mi = 0; mi < 4; ++mi)
#pragma unroll
      for (int ni = 0; ni < 4; ++ni)
        acc[mi][ni] = __builtin_amdgcn_mfma_f32_16x16x32_bf16(af[mi], bf[ni], acc[mi][ni], 0, 0, 0);
    __syncthreads();
  }

#pragma unroll
  for (int ni = 0; ni < 4; ++ni) {
    int col = n0 + wn * 64 + ni * 16 + (lane & 15);
    float bvv = bias ? loadf(bias + col) : 0.f;
#pragma unroll
    for (int mi = 0; mi < 4; ++mi) {
      int rbase = m0 + wm * 64 + mi * 16 + ((lane >> 4) * 4);
#pragma unroll
      for (int r = 0; r < 4; ++r)
        storef(C + (size_t)(rbase + r) * N + col, acc[mi][ni][r] + bvv);
    }
  }
}

// ---------------- MFMA flash attention body, causal, LOAD-BALANCED -----------
// Grid (8, H, B): block x handles the q-tile PAIR (x, 15-x) -> every block
// does exactly 34 key-tile iterations (2176 keys): uniform work regardless of
// block->CU placement. 256 thr / 4 waves; per q-tile: wave w owns rows
// w*32..+31 (two 16-row frags). 64-key tiles; K/V reg-prefetched one ahead.
// Q is ALWAYS bf16 (parked by qkv); K/V native dtype. LDS passed in (shared
// across dtype instantiations, same reason as gemm_body).
#define KSTR 72
#define ATTN_LDS (2 * 64 * KSTR + 4 * 32 * KSTR)   // 18432 ushorts = 36864 B

template <typename TKV>
__device__ __forceinline__ void attn_body(
    const ushortT* __restrict__ Q, const TKV* __restrict__ Kh,
    const TKV* __restrict__ Vh, ushortT* __restrict__ O, ushortT* smem)
{
  ushortT* Ks = smem;                 // [key][dim]   9.2 KB
  ushortT* Vs = smem + 64 * KSTR;     // [dim][key]   9.2 KB
  ushortT* Ps = smem + 2 * 64 * KSTR; // per-wave P  18.4 KB

  const int t = threadIdx.x, w = t >> 6, lane = t & 63;
  const int l15 = lane & 15, quad = lane >> 4;
  const int b = blockIdx.z, h = blockIdx.y;

  bf16x8 onesf;
  {
    ushortT u[8];
#pragma unroll
    for (int j = 0; j < 8; ++j) u[j] = 0x3F80;  // bf16 1.0
    onesf = *(bf16x8*)u;
  }

  const TKV* kb = Kh + (size_t)(b * S_) * D_ + h * DH_;
  const TKV* vb = Vh + (size_t)(b * S_) * D_ + h * DH_;
  ushortT* Pw = Ps + w * (32 * KSTR);

  const int krow = t >> 2, kc = t & 3;   // K staging: row 0..63, chunk 0..3
  const int vk = lane;                   // V staging: key row; dims w*16..+15

  for (int pi = 0; pi < 2; ++pi) {
    const int qt = pi ? (15 - (int)blockIdx.x) : (int)blockIdx.x;
    const int q0 = qt * 128;

    // Q A-frags: rows w*32 + g*16 + l15, k = c*32 + quad*8 .. +7
    bf16x8 qf[2][2];
    {
      const ushortT* qp = Q + ((size_t)(b * S_) + q0 + w * 32 + l15) * D_ + h * DH_ + quad * 8;
#pragma unroll
      for (int g = 0; g < 2; ++g)
#pragma unroll
        for (int c = 0; c < 2; ++c) {
          ushortT u[8];
          load8b(qp + (size_t)g * 16 * D_ + c * 32, u);
          qf[g][c] = *(bf16x8*)u;
        }
    }

    f32x4 oac[2][4];
#pragma unroll
    for (int g = 0; g < 2; ++g)
#pragma unroll
      for (int ni = 0; ni < 4; ++ni) oac[g][ni] = (f32x4){0.f, 0.f, 0.f, 0.f};
    f32x4 lac[2];
    lac[0] = (f32x4){0.f, 0.f, 0.f, 0.f};
    lac[1] = (f32x4){0.f, 0.f, 0.f, 0.f};

    ushortT kr[16], vr[16];
    const int t0max = q0 + 64;

    // prefetch tile 0
    {
      const TKV* kp = kb + (size_t)krow * D_ + kc * 8;
      load8b(kp, kr); load8b(kp + 32, kr + 8);
      const TKV* vp = vb + (size_t)vk * D_ + w * 16;
      load16b(vp, vr);
    }

    for (int t0 = 0; t0 <= t0max; t0 += 64) {
      // ---- write prefetched regs -> LDS ----
      *(uint4*)&Ks[krow * KSTR + kc * 8] = *(uint4*)kr;
      *(uint4*)&Ks[krow * KSTR + kc * 8 + 32] = *(uint4*)(kr + 8);
#pragma unroll
      for (int j = 0; j < 16; ++j) Vs[(w * 16 + j) * KSTR + vk] = vr[j];
      __syncthreads();

      // ---- prefetch next tile (latency hidden behind this tile's compute) --
      if (t0 + 64 <= t0max) {
        const TKV* kp = kb + (size_t)(t0 + 64 + krow) * D_ + kc * 8;
        load8b(kp, kr); load8b(kp + 32, kr + 8);
        const TKV* vp = vb + (size_t)(t0 + 64 + vk) * D_ + w * 16;
        load16b(vp, vr);
      }

      // ---- S = Q K^T ----
      f32x4 sac[2][4];
#pragma unroll
      for (int g = 0; g < 2; ++g)
#pragma unroll
        for (int ni = 0; ni < 4; ++ni) sac[g][ni] = (f32x4){0.f, 0.f, 0.f, 0.f};
      __builtin_amdgcn_s_setprio(1);
#pragma unroll
      for (int c = 0; c < 2; ++c)
#pragma unroll
        for (int ni = 0; ni < 4; ++ni) {
          bf16x8 bk = *(const bf16x8*)&Ks[(16 * ni + l15) * KSTR + c * 32 + quad * 8];
#pragma unroll
          for (int g = 0; g < 2; ++g)
            sac[g][ni] = __builtin_amdgcn_mfma_f32_16x16x32_bf16(qf[g][c], bk, sac[g][ni], 0, 0, 0);
        }
      __builtin_amdgcn_s_setprio(0);

      // ---- causal mask (only the last two tiles; block-uniform branch) ----
      if (t0 >= q0) {
        int koff = t0 - q0;
#pragma unroll
        for (int g = 0; g < 2; ++g) {
          int rowloc = w * 32 + g * 16 + quad * 4;
#pragma unroll
          for (int ni = 0; ni < 4; ++ni) {
            int kcol = koff + 16 * ni + l15;
#pragma unroll
            for (int r = 0; r < 4; ++r)
              if (kcol > rowloc + r) sac[g][ni][r] = -1e30f;
          }
        }
      }

      // ---- P = exp(0.125*s) -> per-wave LDS (C-layout scatter) ----
#pragma unroll
      for (int g = 0; g < 2; ++g)
#pragma unroll
        for (int ni = 0; ni < 4; ++ni)
#pragma unroll
          for (int r = 0; r < 4; ++r) {
            float p = __expf(sac[g][ni][r] * 0.125f);
            Pw[(g * 16 + quad * 4 + r) * KSTR + 16 * ni + l15] = f2b(p);
          }

      // ---- O += P V ; rowsum += P @ ones  (per-wave LDS, no barrier) ----
      __builtin_amdgcn_s_setprio(1);
#pragma unroll
      for (int g = 0; g < 2; ++g)
#pragma unroll
        for (int c = 0; c < 2; ++c) {
          bf16x8 pa = *(const bf16x8*)&Pw[(g * 16 + l15) * KSTR + c * 32 + quad * 8];
          lac[g] = __builtin_amdgcn_mfma_f32_16x16x32_bf16(pa, onesf, lac[g], 0, 0, 0);
#pragma unroll
          for (int ni = 0; ni < 4; ++ni) {
            bf16x8 bv = *(const bf16x8*)&Vs[(16 * ni + l15) * KSTR + c * 32 + quad * 8];
            oac[g][ni] = __builtin_amdgcn_mfma_f32_16x16x32_bf16(pa, bv, oac[g][ni], 0, 0, 0);
          }
        }
      __builtin_amdgcn_s_setprio(0);
      __syncthreads();
    }

    // ---- epilogue: row = q0 + w*32 + g*16 + quad*4 + r, dim = 16*ni + l15 --
#pragma unroll
    for (int g = 0; g < 2; ++g)
#pragma unroll
      for (int r = 0; r < 4; ++r) {
        float inv = 1.f / lac[g][r];
        ushortT* op = O + ((size_t)(b * S_) + q0 + w * 32 + g * 16 + quad * 4 + r) * D_ + h * DH_;
#pragma unroll
        for (int ni = 0; ni < 4; ++ni)
          op[16 * ni + l15] = f2b(oac[g][ni][r] * inv);
      }
    // LDS reuse across pi is safe: last inner-loop iteration ends with
    // __syncthreads() after all PV reads; epilogue touches no LDS.
  }
}

// ---------------- merged flag-branching wrappers (one launch per stage) ------
__global__ __launch_bounds__(256) void qkv_any(
    const void* x, const void* Wq, const void* Wk, const void* Wv,
    const void* bq, const void* bv, void* outp, const unsigned int* flag) {
  __shared__ __align__(16) ushortT smem[GEMM_LDS];
  int z = blockIdx.z;
  if (*flag == FLAG_BF16) {
    ushortT* o = (ushortT*)outp;
    ushortT* q = o;                         // parked in a-region
    ushortT* k = o + (size_t)8388608;
    ushortT* v = o + (size_t)16777216;
    if (z == 0)      gemm_body<ushortT, ushortT>((const ushortT*)x, (const ushortT*)Wq, (const ushortT*)bq, q, smem);
    else if (z == 1) gemm_body<ushortT, ushortT>((const ushortT*)x, (const ushortT*)Wk, nullptr, k, smem);
    else             gemm_body<ushortT, ushortT>((const ushortT*)x, (const ushortT*)Wv, (const ushortT*)bv, v, smem);
  } else {
    float* of = (float*)outp;
    const ushortT* xb = (const ushortT*)outp;            // a-region, first half
    ushortT* q = (ushortT*)outp + (size_t)8388608;       // a-region, second half
    float* k = of + (size_t)8388608;
    float* v = of + (size_t)16777216;
    if (z == 0)      gemm_body<float, ushortT>(xb, (const float*)Wq, (const float*)bq, q, smem);
    else if (z == 1) gemm_body<float, float>(xb, (const float*)Wk, nullptr, k, smem);
    else             gemm_body<float, float>(xb, (const float*)Wv, (const float*)bv, v, smem);
  }
}

__global__ __launch_bounds__(256, 4) void attn_any(
    void* outp, ushortT* O, const unsigned int* flag) {
  __shared__ __align__(16) ushortT smem[ATTN_LDS];
  if (*flag == FLAG_BF16) {
    ushortT* o = (ushortT*)outp;
    attn_body<ushortT>(o, o + (size_t)8388608, o + (size_t)16777216, O, smem);
  } else {
    const ushortT* q = (const ushortT*)outp + (size_t)8388608;
    const float* of = (const float*)outp;
    attn_body<float>(q, of + (size_t)8388608, of + (size_t)16777216, O, smem);
  }
}

__global__ __launch_bounds__(256) void proj_any(
    const ushortT* A, const void* Wc, const void* bc, void* outp,
    const unsigned int* flag) {
  __shared__ __align__(16) ushortT smem[GEMM_LDS];
  if (*flag == FLAG_BF16)
    gemm_body<ushortT, ushortT>(A, (const ushortT*)Wc, (const ushortT*)bc, (ushortT*)outp, smem);
  else
    gemm_body<float, float>(A, (const float*)Wc, (const float*)bc, (float*)outp, smem);
}

// -----------------------------------------------------------------------------
// ws: [0..256) dtype flag; [256..) attention output (bf16, 16.8 MB).
// f32 d_out a-region: [0..16.78M) xb (x as bf16); [16.78..33.55M) q (bf16).
// bf16 d_out a-region: q parked bf16 in [0..16.78M).
extern "C" void kernel_launch(void* const* d_in, const int* in_sizes, int n_in,
                              void* d_out, int out_size, void* d_ws, size_t ws_size,
                              hipStream_t stream) {
  (void)in_sizes; (void)n_in; (void)out_size; (void)ws_size;

  unsigned int* flagp = (unsigned int*)d_ws;
  ushortT* attn_ws = (ushortT*)((char*)d_ws + 256);

  detect_dtype<<<1, 64, 0, stream>>>((const unsigned int*)d_in[0], flagp);
  cvt_x_f32<<<2048, 256, 0, stream>>>((const float*)d_in[0], (ushortT*)d_out, flagp);

  dim3 gq(MROWS / 128, D_ / 128, 3);  // (64, 8, 3) fused QKV
  dim3 gp(MROWS / 128, D_ / 128);     // (64, 8)    output proj
  dim3 ga(S_ / 256, H_, B_);          // (8, 16, 4) paired causal q-tiles

  qkv_any<<<gq, 256, 0, stream>>>(d_in[0], d_in[1], d_in[3], d_in[4],
                                  d_in[2], d_in[5], d_out, flagp);
  attn_any<<<ga, 256, 0, stream>>>(d_out, attn_ws, flagp);
  proj_any<<<gp, 256, 0, stream>>>(attn_ws, d_in[6], d_in[7], d_out, flagp);
}

// Round 5
// 382.788 us; speedup vs baseline: 1.1408x; 1.1408x over previous
//
#include <hip/hip_runtime.h>
#include <stdint.h>

#define B_ 4
#define S_ 2048
#define D_ 1024
#define H_ 16
#define DH_ 64
#define MROWS (B_*S_)   // 8192

typedef unsigned short ushortT;
typedef __attribute__((ext_vector_type(8))) short bf16x8;
typedef __attribute__((ext_vector_type(4))) float f32x4;

#define FLAG_BF16 1u
#define FLAG_F32  2u

__device__ __forceinline__ float b2f(ushortT u) {
  union { unsigned int i; float f; } v; v.i = ((unsigned int)u) << 16; return v.f;
}
__device__ __forceinline__ ushortT f2b(float f) {
  union { float f; unsigned int i; } v; v.f = f;
  unsigned int r = v.i + 0x7fffu + ((v.i >> 16) & 1u);
  return (ushortT)(r >> 16);
}

// scalar load -> float
__device__ __forceinline__ float loadf(const ushortT* p) { return b2f(*p); }
__device__ __forceinline__ float loadf(const float* p)   { return *p; }
// scalar -> bf16 bits (as uint)
__device__ __forceinline__ unsigned int tob(ushortT u) { return u; }
__device__ __forceinline__ unsigned int tob(float f)   { return f2b(f); }

// 8-wide load -> 8 bf16 ushorts (bf16: pure copy, no VALU)
__device__ __forceinline__ void load8b(const ushortT* p, ushortT* u) {
  *(uint4*)u = *(const uint4*)p;
}
__device__ __forceinline__ void load8b(const float* p, ushortT* u) {
  float4 a = ((const float4*)p)[0], b = ((const float4*)p)[1];
  u[0] = f2b(a.x); u[1] = f2b(a.y); u[2] = f2b(a.z); u[3] = f2b(a.w);
  u[4] = f2b(b.x); u[5] = f2b(b.y); u[6] = f2b(b.z); u[7] = f2b(b.w);
}
template <typename T>
__device__ __forceinline__ void load16b(const T* p, ushortT* u) {
  load8b(p, u); load8b(p + 8, u + 8);
}

// dtype-generic store
__device__ __forceinline__ void storef(ushortT* p, float v) { *p = f2b(v); }
__device__ __forceinline__ void storef(float* p, float v)   { *p = v; }

// async global->LDS, 16 bytes per lane (dest = uniform base + lane*16)
__device__ __forceinline__ void gload16(const ushortT* g, ushortT* l) {
  __builtin_amdgcn_global_load_lds(
      (const __attribute__((address_space(1))) void*)g,
      (__attribute__((address_space(3))) void*)l, 16, 0, 0);
}

// ---------------- dtype probe ------------------------------------------------
__global__ void detect_dtype(const unsigned int* __restrict__ xw,
                             unsigned int* __restrict__ flag) {
  int lane = threadIdx.x;
  int cnt = 0;
  for (int i = lane; i < 2048; i += 64) {
    unsigned int e = (xw[i] >> 7) & 0xFFu;
    cnt += (e >= 0x68u && e <= 0x8Au) ? 1 : 0;
  }
#pragma unroll
  for (int off = 32; off; off >>= 1) cnt += __shfl_down(cnt, off);
  if (lane == 0) *flag = (cnt > 1024) ? FLAG_BF16 : FLAG_F32;
}

// ---------------- x -> bf16 one-time convert (f32 pipeline only) -------------
__global__ __launch_bounds__(256) void cvt_x_f32(
    const float* __restrict__ x, ushortT* __restrict__ xb,
    const unsigned int* __restrict__ flag) {
  if (*flag != FLAG_F32) return;
  const int total = MROWS * D_ / 8;  // 8-elem chunks
  for (int i = blockIdx.x * 256 + threadIdx.x; i < total; i += gridDim.x * 256) {
    float4 a = ((const float4*)x)[2 * i], b = ((const float4*)x)[2 * i + 1];
    ushortT u[8];
    u[0] = f2b(a.x); u[1] = f2b(a.y); u[2] = f2b(a.z); u[3] = f2b(a.w);
    u[4] = f2b(b.x); u[5] = f2b(b.y); u[6] = f2b(b.z); u[7] = f2b(b.w);
    ((uint4*)xb)[i] = *(uint4*)u;
  }
}

// ---------------- MFMA GEMM body: C[M,N] = A[M,K] @ B[K,N] + bias ------------
// A is ALWAYS bf16 in global. Staged via global_load_lds_dwordx4 into linear
// [row][32] LDS. B (weights, native dtype) reg-staged transposed, prefetched
// one K-step ahead. 128x128 tile, BK=32, 256 threads (2x2 waves of 64x64).
// LDS passed in from wrapper so all template instantiations SHARE it.
#define BK 32
#define BSTRIDE 40
#define GEMM_LDS (128 * BK + 128 * BSTRIDE)   // 9216 ushorts = 18432 B

template <typename TB, typename TOUT>
__device__ __forceinline__ void gemm_body(
    const ushortT* __restrict__ A, const TB* __restrict__ Bm,
    const TB* __restrict__ bias, TOUT* __restrict__ C, ushortT* smem)
{
  const int K = 1024, N = 1024;
  ushortT* As = smem;              // 128*BK, linear (global_load_lds dest)
  ushortT* Bs = smem + 128 * BK;   // 128*BSTRIDE, padded
  int m0 = blockIdx.x * 128;
  int n0 = blockIdx.y * 128;
  int t = threadIdx.x;
  int lane = t & 63;
  int w = t >> 6;
  int wm = w >> 1, wn = w & 1;

  f32x4 acc[4][4] = {};

  // A: per-lane global src; wave-uniform LDS dest
  const ushortT* a_src0 = A + (size_t)(m0 + (t >> 2)) * K + (t & 3) * 8;
  const ushortT* a_src1 = a_src0 + (size_t)64 * K;
  ushortT* a_dst0 = &As[(16 * w) * BK];
  ushortT* a_dst1 = &As[(64 + 16 * w) * BK];

  // B: thread covers col cB, rows r0..r0+15 of each K-slab
  int cB = t & 127, r0 = (t >> 7) * 16;
  const TB* Bp0 = Bm + (size_t)r0 * N + n0 + cB;

  // prefetch B regs for kt=0
  TB breg[16];
#pragma unroll
  for (int j = 0; j < 16; ++j) breg[j] = Bp0[(size_t)j * N];

  for (int kt = 0; kt < K; kt += BK) {
    // stage A (async DMA, no VALU)
    gload16(a_src0 + kt, a_dst0);
    gload16(a_src1 + kt, a_dst1);
    // stage B from prefetched regs (transposed pack)
    {
      unsigned int* bd = (unsigned int*)&Bs[cB * BSTRIDE + r0];
#pragma unroll
      for (int j = 0; j < 8; ++j) {
        unsigned int lo = tob(breg[2 * j]);
        unsigned int hi = tob(breg[2 * j + 1]);
        bd[j] = lo | (hi << 16);
      }
    }
    __syncthreads();  // drains vmcnt (gll) + lgkm (ds_write)

    // prefetch next B tile (latency hides under MFMAs below)
    if (kt + BK < K) {
      const TB* bp = Bp0 + (size_t)(kt + BK) * N;
#pragma unroll
      for (int j = 0; j < 16; ++j) breg[j] = bp[(size_t)j * N];
    }

    int kq = (lane >> 4) * 8;
    int lm = lane & 15;
    bf16x8 af[4], bf[4];
#pragma unroll
    for (int mi = 0; mi < 4; ++mi)
      af[mi] = *(const bf16x8*)&As[(wm * 64 + mi * 16 + lm) * BK + kq];
#pragma unroll
    for (int ni = 0; ni < 4; ++ni)
      bf[ni] = *(const bf16x8*)&Bs[(wn * 64 + ni * 16 + lm) * BSTRIDE + kq];
#pragma unroll
    for (int mi = 0; mi < 4; ++mi)
#pragma unroll
      for (int ni = 0; ni < 4; ++ni)
        acc[mi][ni] = __builtin_amdgcn_mfma_f32_16x16x32_bf16(af[mi], bf[ni], acc[mi][ni], 0, 0, 0);
    __syncthreads();
  }

#pragma unroll
  for (int ni = 0; ni < 4; ++ni) {
    int col = n0 + wn * 64 + ni * 16 + (lane & 15);
    float bvv = bias ? loadf(bias + col) : 0.f;
#pragma unroll
    for (int mi = 0; mi < 4; ++mi) {
      int rbase = m0 + wm * 64 + mi * 16 + ((lane >> 4) * 4);
#pragma unroll
      for (int r = 0; r < 4; ++r)
        storef(C + (size_t)(rbase + r) * N + col, acc[mi][ni][r] + bvv);
    }
  }
}

// ---------------- MFMA flash attention body, causal, LOAD-BALANCED -----------
// 512 thr / 8 waves; wave w owns 16 q-rows (w*16..+15) -> twice the resident
// waves per CU vs the 4-wave version (grid 512 blocks = 2 blocks/CU cap, so
// waves/block is the only occupancy lever). Block handles q-tile PAIR
// (x, 15-x): exactly 34 key-tile iterations regardless of x.
// Q is ALWAYS bf16 (parked by qkv); K/V native dtype.
#define KSTR 72
#define ATTN_LDS (2 * 64 * KSTR + 8 * 16 * KSTR)   // 18432 ushorts = 36864 B

template <typename TKV>
__device__ __forceinline__ void attn_body(
    const ushortT* __restrict__ Q, const TKV* __restrict__ Kh,
    const TKV* __restrict__ Vh, ushortT* __restrict__ O, ushortT* smem,
    int x, int h, int b)
{
  ushortT* Ks = smem;                 // [key][dim]   9.2 KB
  ushortT* Vs = smem + 64 * KSTR;     // [dim][key]   9.2 KB
  ushortT* Ps = smem + 2 * 64 * KSTR; // per-wave P  18.4 KB

  const int t = threadIdx.x, w = t >> 6, lane = t & 63;
  const int l15 = lane & 15, quad = lane >> 4;

  bf16x8 onesf;
  {
    ushortT u[8];
#pragma unroll
    for (int j = 0; j < 8; ++j) u[j] = 0x3F80;  // bf16 1.0
    onesf = *(bf16x8*)u;
  }

  const TKV* kb = Kh + (size_t)(b * S_) * D_ + h * DH_;
  const TKV* vb = Vh + (size_t)(b * S_) * D_ + h * DH_;
  ushortT* Pw = Ps + w * (16 * KSTR);

  const int krow = t >> 3, kc = t & 7;   // K staging: row 0..63, chunk 0..7
  const int vk = lane;                   // V staging: key row; dims w*8..+7

  for (int pi = 0; pi < 2; ++pi) {
    const int qt = pi ? (15 - x) : x;
    const int q0 = qt * 128;

    // Q A-frags: rows w*16 + l15, k = c*32 + quad*8 .. +7 (raw, unscaled)
    bf16x8 qf[2];
    {
      const ushortT* qp = Q + ((size_t)(b * S_) + q0 + w * 16 + l15) * D_ + h * DH_ + quad * 8;
#pragma unroll
      for (int c = 0; c < 2; ++c) {
        ushortT u[8];
        load8b(qp + c * 32, u);
        qf[c] = *(bf16x8*)u;
      }
    }

    f32x4 oac[4];
#pragma unroll
    for (int ni = 0; ni < 4; ++ni) oac[ni] = (f32x4){0.f, 0.f, 0.f, 0.f};
    f32x4 lac = (f32x4){0.f, 0.f, 0.f, 0.f};

    ushortT kr[8], vr[8];
    const int t0max = q0 + 64;

    // prefetch tile 0
    {
      const TKV* kp = kb + (size_t)krow * D_ + kc * 8;
      load8b(kp, kr);
      const TKV* vp = vb + (size_t)vk * D_ + w * 8;
      load8b(vp, vr);
    }

    for (int t0 = 0; t0 <= t0max; t0 += 64) {
      // ---- write prefetched regs -> LDS ----
      *(uint4*)&Ks[krow * KSTR + kc * 8] = *(uint4*)kr;
#pragma unroll
      for (int j = 0; j < 8; ++j) Vs[(w * 8 + j) * KSTR + vk] = vr[j];
      __syncthreads();

      // ---- prefetch next tile (latency hidden behind this tile's compute) --
      if (t0 + 64 <= t0max) {
        const TKV* kp = kb + (size_t)(t0 + 64 + krow) * D_ + kc * 8;
        load8b(kp, kr);
        const TKV* vp = vb + (size_t)(t0 + 64 + vk) * D_ + w * 8;
        load8b(vp, vr);
      }

      // ---- S = Q K^T ----
      f32x4 sac[4];
#pragma unroll
      for (int ni = 0; ni < 4; ++ni) sac[ni] = (f32x4){0.f, 0.f, 0.f, 0.f};
      __builtin_amdgcn_s_setprio(1);
#pragma unroll
      for (int c = 0; c < 2; ++c)
#pragma unroll
        for (int ni = 0; ni < 4; ++ni) {
          bf16x8 bk = *(const bf16x8*)&Ks[(16 * ni + l15) * KSTR + c * 32 + quad * 8];
          sac[ni] = __builtin_amdgcn_mfma_f32_16x16x32_bf16(qf[c], bk, sac[ni], 0, 0, 0);
        }
      __builtin_amdgcn_s_setprio(0);

      // ---- causal mask (only the last two tiles; block-uniform branch) ----
      if (t0 >= q0) {
        int koff = t0 - q0;
        int rowloc = w * 16 + quad * 4;
#pragma unroll
        for (int ni = 0; ni < 4; ++ni) {
          int kcol = koff + 16 * ni + l15;
#pragma unroll
          for (int r = 0; r < 4; ++r)
            if (kcol > rowloc + r) sac[ni][r] = -1e30f;
        }
      }

      // ---- P = exp(0.125*s) -> per-wave LDS (C-layout scatter) ----
#pragma unroll
      for (int ni = 0; ni < 4; ++ni)
#pragma unroll
        for (int r = 0; r < 4; ++r) {
          float p = __expf(sac[ni][r] * 0.125f);
          Pw[(quad * 4 + r) * KSTR + 16 * ni + l15] = f2b(p);
        }

      // ---- O += P V ; rowsum += P @ ones  (per-wave LDS, no barrier) ----
      __builtin_amdgcn_s_setprio(1);
#pragma unroll
      for (int c = 0; c < 2; ++c) {
        bf16x8 pa = *(const bf16x8*)&Pw[l15 * KSTR + c * 32 + quad * 8];
        lac = __builtin_amdgcn_mfma_f32_16x16x32_bf16(pa, onesf, lac, 0, 0, 0);
#pragma unroll
        for (int ni = 0; ni < 4; ++ni) {
          bf16x8 bv = *(const bf16x8*)&Vs[(16 * ni + l15) * KSTR + c * 32 + quad * 8];
          oac[ni] = __builtin_amdgcn_mfma_f32_16x16x32_bf16(pa, bv, oac[ni], 0, 0, 0);
        }
      }
      __builtin_amdgcn_s_setprio(0);
      __syncthreads();
    }

    // ---- epilogue: row = q0 + w*16 + quad*4 + r, dim = 16*ni + l15 ----
#pragma unroll
    for (int r = 0; r < 4; ++r) {
      float inv = 1.f / lac[r];
      ushortT* op = O + ((size_t)(b * S_) + q0 + w * 16 + quad * 4 + r) * D_ + h * DH_;
#pragma unroll
      for (int ni = 0; ni < 4; ++ni)
        op[16 * ni + l15] = f2b(oac[ni][r] * inv);
    }
    // LDS reuse across pi is safe: last inner iteration ends with
    // __syncthreads() after all PV reads; epilogue touches no LDS.
  }
}

// ---------------- merged flag-branching wrappers (one launch per stage) ------
__global__ __launch_bounds__(256) void qkv_any(
    const void* x, const void* Wq, const void* Wk, const void* Wv,
    const void* bq, const void* bv, void* outp, const unsigned int* flag) {
  __shared__ __align__(16) ushortT smem[GEMM_LDS];
  int z = blockIdx.z;
  if (*flag == FLAG_BF16) {
    ushortT* o = (ushortT*)outp;
    ushortT* q = o;                         // parked in a-region
    ushortT* k = o + (size_t)8388608;
    ushortT* v = o + (size_t)16777216;
    if (z == 0)      gemm_body<ushortT, ushortT>((const ushortT*)x, (const ushortT*)Wq, (const ushortT*)bq, q, smem);
    else if (z == 1) gemm_body<ushortT, ushortT>((const ushortT*)x, (const ushortT*)Wk, nullptr, k, smem);
    else             gemm_body<ushortT, ushortT>((const ushortT*)x, (const ushortT*)Wv, (const ushortT*)bv, v, smem);
  } else {
    float* of = (float*)outp;
    const ushortT* xb = (const ushortT*)outp;            // a-region, first half
    ushortT* q = (ushortT*)outp + (size_t)8388608;       // a-region, second half
    float* k = of + (size_t)8388608;
    float* v = of + (size_t)16777216;
    if (z == 0)      gemm_body<float, ushortT>(xb, (const float*)Wq, (const float*)bq, q, smem);
    else if (z == 1) gemm_body<float, float>(xb, (const float*)Wk, nullptr, k, smem);
    else             gemm_body<float, float>(xb, (const float*)Wv, (const float*)bv, v, smem);
  }
}

// XCD-aware remap: dispatch sends bid -> XCD (bid % 8); the 8 x-blocks that
// share one (b,h)'s K/V slab have consecutive bids and would otherwise land
// on 8 DIFFERENT XCDs (zero L2 sharing; round-4 FETCH 297 MB vs ~84 MB ideal).
// lid = (bid&7)*64 + bid>>3 (bijective, 512=8*64) puts all 8 x-blocks of a
// (b,h) plus 8 consecutive (b,h) groups on ONE XCD.
__global__ __launch_bounds__(512, 2) void attn_any(
    void* outp, ushortT* O, const unsigned int* flag) {
  __shared__ __align__(16) ushortT smem[ATTN_LDS];
  int bid = (int)blockIdx.x + 8 * (int)blockIdx.y + 128 * (int)blockIdx.z;
  int lid = (bid & 7) * 64 + (bid >> 3);
  int x = lid & 7, h = (lid >> 3) & 15, b = lid >> 7;
  if (*flag == FLAG_BF16) {
    ushortT* o = (ushortT*)outp;
    attn_body<ushortT>(o, o + (size_t)8388608, o + (size_t)16777216, O, smem, x, h, b);
  } else {
    const ushortT* q = (const ushortT*)outp + (size_t)8388608;
    const float* of = (const float*)outp;
    attn_body<float>(q, of + (size_t)8388608, of + (size_t)16777216, O, smem, x, h, b);
  }
}

__global__ __launch_bounds__(256) void proj_any(
    const ushortT* A, const void* Wc, const void* bc, void* outp,
    const unsigned int* flag) {
  __shared__ __align__(16) ushortT smem[GEMM_LDS];
  if (*flag == FLAG_BF16)
    gemm_body<ushortT, ushortT>(A, (const ushortT*)Wc, (const ushortT*)bc, (ushortT*)outp, smem);
  else
    gemm_body<float, float>(A, (const float*)Wc, (const float*)bc, (float*)outp, smem);
}

// -----------------------------------------------------------------------------
// ws: [0..256) dtype flag; [256..) attention output (bf16, 16.8 MB).
// f32 d_out a-region: [0..16.78M) xb (x as bf16); [16.78..33.55M) q (bf16).
// bf16 d_out a-region: q parked bf16 in [0..16.78M).
extern "C" void kernel_launch(void* const* d_in, const int* in_sizes, int n_in,
                              void* d_out, int out_size, void* d_ws, size_t ws_size,
                              hipStream_t stream) {
  (void)in_sizes; (void)n_in; (void)out_size; (void)ws_size;

  unsigned int* flagp = (unsigned int*)d_ws;
  ushortT* attn_ws = (ushortT*)((char*)d_ws + 256);

  detect_dtype<<<1, 64, 0, stream>>>((const unsigned int*)d_in[0], flagp);
  cvt_x_f32<<<2048, 256, 0, stream>>>((const float*)d_in[0], (ushortT*)d_out, flagp);

  dim3 gq(MROWS / 128, D_ / 128, 3);  // (64, 8, 3) fused QKV
  dim3 gp(MROWS / 128, D_ / 128);     // (64, 8)    output proj
  dim3 ga(S_ / 256, H_, B_);          // (8, 16, 4) paired causal q-tiles

  qkv_any<<<gq, 256, 0, stream>>>(d_in[0], d_in[1], d_in[3], d_in[4],
                                  d_in[2], d_in[5], d_out, flagp);
  attn_any<<<ga, 512, 0, stream>>>(d_out, attn_ws, flagp);
  proj_any<<<gp, 256, 0, stream>>>(attn_ws, d_in[6], d_in[7], d_out, flagp);
}

// Round 6
// 334.430 us; speedup vs baseline: 1.3057x; 1.1446x over previous
//
#include <hip/hip_runtime.h>
#include <stdint.h>

#define B_ 4
#define S_ 2048
#define D_ 1024
#define H_ 16
#define DH_ 64
#define MROWS (B_*S_)   // 8192

typedef unsigned short ushortT;
typedef __attribute__((ext_vector_type(8))) short bf16x8;
typedef __attribute__((ext_vector_type(4))) float f32x4;

#define FLAG_BF16 1u
#define FLAG_F32  2u

__device__ __forceinline__ float b2f(ushortT u) {
  union { unsigned int i; float f; } v; v.i = ((unsigned int)u) << 16; return v.f;
}
__device__ __forceinline__ ushortT f2b(float f) {
  union { float f; unsigned int i; } v; v.f = f;
  unsigned int r = v.i + 0x7fffu + ((v.i >> 16) & 1u);
  return (ushortT)(r >> 16);
}

// scalar load -> float
__device__ __forceinline__ float loadf(const ushortT* p) { return b2f(*p); }
__device__ __forceinline__ float loadf(const float* p)   { return *p; }
// scalar -> bf16 bits (as uint)
__device__ __forceinline__ unsigned int tob(ushortT u) { return u; }
__device__ __forceinline__ unsigned int tob(float f)   { return f2b(f); }

// 8-wide load -> 8 bf16 ushorts (bf16: pure copy, no VALU)
__device__ __forceinline__ void load8b(const ushortT* p, ushortT* u) {
  *(uint4*)u = *(const uint4*)p;
}
__device__ __forceinline__ void load8b(const float* p, ushortT* u) {
  float4 a = ((const float4*)p)[0], b = ((const float4*)p)[1];
  u[0] = f2b(a.x); u[1] = f2b(a.y); u[2] = f2b(a.z); u[3] = f2b(a.w);
  u[4] = f2b(b.x); u[5] = f2b(b.y); u[6] = f2b(b.z); u[7] = f2b(b.w);
}
template <typename T>
__device__ __forceinline__ void load16b(const T* p, ushortT* u) {
  load8b(p, u); load8b(p + 8, u + 8);
}

// dtype-generic store
__device__ __forceinline__ void storef(ushortT* p, float v) { *p = f2b(v); }
__device__ __forceinline__ void storef(float* p, float v)   { *p = v; }

// async global->LDS, 16 bytes per lane (dest = uniform base + lane*16)
__device__ __forceinline__ void gload16(const ushortT* g, ushortT* l) {
  __builtin_amdgcn_global_load_lds(
      (const __attribute__((address_space(1))) void*)g,
      (__attribute__((address_space(3))) void*)l, 16, 0, 0);
}

// ---------------- dtype probe ------------------------------------------------
__global__ void detect_dtype(const unsigned int* __restrict__ xw,
                             unsigned int* __restrict__ flag) {
  int lane = threadIdx.x;
  int cnt = 0;
  for (int i = lane; i < 2048; i += 64) {
    unsigned int e = (xw[i] >> 7) & 0xFFu;
    cnt += (e >= 0x68u && e <= 0x8Au) ? 1 : 0;
  }
#pragma unroll
  for (int off = 32; off; off >>= 1) cnt += __shfl_down(cnt, off);
  if (lane == 0) *flag = (cnt > 1024) ? FLAG_BF16 : FLAG_F32;
}

// ---------------- x -> bf16 one-time convert (f32 pipeline only) -------------
__global__ __launch_bounds__(256) void cvt_x_f32(
    const float* __restrict__ x, ushortT* __restrict__ xb,
    const unsigned int* __restrict__ flag) {
  if (*flag != FLAG_F32) return;
  const int total = MROWS * D_ / 8;  // 8-elem chunks
  for (int i = blockIdx.x * 256 + threadIdx.x; i < total; i += gridDim.x * 256) {
    float4 a = ((const float4*)x)[2 * i], b = ((const float4*)x)[2 * i + 1];
    ushortT u[8];
    u[0] = f2b(a.x); u[1] = f2b(a.y); u[2] = f2b(a.z); u[3] = f2b(a.w);
    u[4] = f2b(b.x); u[5] = f2b(b.y); u[6] = f2b(b.z); u[7] = f2b(b.w);
    ((uint4*)xb)[i] = *(uint4*)u;
  }
}

// ---------------- W -> W^T bf16 one-time transpose ---------------------------
// W[k][n] (native dtype) -> WT[n][k] (bf16). 64x64 tiles via padded LDS.
// z = 0..2 -> Wq,Wk,Wv into dst0 + z*1M ushorts; z = 3 -> Wc into dstc.
__global__ __launch_bounds__(256) void transpose_w(
    const void* W0, const void* W1, const void* W2, const void* W3,
    ushortT* dst0, ushortT* dstc, const unsigned int* flag) {
  __shared__ ushortT tile[64][72];
  int z = blockIdx.z;
  const void* W = (z == 0) ? W0 : (z == 1) ? W1 : (z == 2) ? W2 : W3;
  ushortT* dst = (z < 3) ? dst0 + (size_t)z * 1048576 : dstc;
  int n0 = blockIdx.x * 64, k0 = blockIdx.y * 64;
  int t = threadIdx.x;
  bool isb = (*flag == FLAG_BF16);
  for (int s = t; s < 512; s += 256) {
    int kr = s >> 3, nc = (s & 7) * 8;
    ushortT u[8];
    if (isb) load8b((const ushortT*)W + (size_t)(k0 + kr) * D_ + n0 + nc, u);
    else     load8b((const float*)W   + (size_t)(k0 + kr) * D_ + n0 + nc, u);
#pragma unroll
    for (int j = 0; j < 8; ++j) tile[kr][nc + j] = u[j];
  }
  __syncthreads();
  for (int s = t; s < 512; s += 256) {
    int nr = s >> 3, kc = (s & 7) * 8;
    ushortT u[8];
#pragma unroll
    for (int j = 0; j < 8; ++j) u[j] = tile[kc + j][nr];
    *(uint4*)(dst + (size_t)(n0 + nr) * D_ + k0 + kc) = *(uint4*)u;
  }
}

// ---------------- MFMA GEMM, both operands bf16, B pre-transposed ------------
// C[M,N] = A[M,K] @ B[K,N] + bias, with Bt[n][k] = B[k][n] in global (bf16).
// A and Bt staged IDENTICALLY via global_load_lds_dwordx4 into linear
// [row][32] LDS: zero staging VALU, zero ds_write (m97 2-barrier structure).
// 128x128 tile, BK=32, 256 threads (2x2 waves of 64x64).
#define GEMM_BT_LDS (2 * 128 * 32)   // 8192 ushorts = 16 KB

template <typename TBIAS, typename TOUT>
__device__ __forceinline__ void gemm_bt(
    const ushortT* __restrict__ A, const ushortT* __restrict__ Bt,
    const TBIAS* __restrict__ bias, TOUT* __restrict__ C, ushortT* smem)
{
  const int K = 1024, N = 1024;
  ushortT* As = smem;             // [128][32]
  ushortT* Bs = smem + 128 * 32;  // [128][32]
  int m0 = blockIdx.x * 128;
  int n0 = blockIdx.y * 128;
  int t = threadIdx.x;
  int lane = t & 63;
  int w = t >> 6;
  int wm = w >> 1, wn = w & 1;

  f32x4 acc[4][4] = {};

  // per-lane global srcs; wave-uniform LDS dests (row t>>2, 8-elem slot t&3)
  const ushortT* a_src0 = A  + (size_t)(m0 + (t >> 2)) * K + (t & 3) * 8;
  const ushortT* a_src1 = a_src0 + (size_t)64 * K;
  const ushortT* b_src0 = Bt + (size_t)(n0 + (t >> 2)) * K + (t & 3) * 8;
  const ushortT* b_src1 = b_src0 + (size_t)64 * K;
  ushortT* a_dst0 = &As[(16 * w) * 32];
  ushortT* a_dst1 = &As[(64 + 16 * w) * 32];
  ushortT* b_dst0 = &Bs[(16 * w) * 32];
  ushortT* b_dst1 = &Bs[(64 + 16 * w) * 32];

  for (int kt = 0; kt < K; kt += 32) {
    gload16(a_src0 + kt, a_dst0);
    gload16(a_src1 + kt, a_dst1);
    gload16(b_src0 + kt, b_dst0);
    gload16(b_src1 + kt, b_dst1);
    __syncthreads();  // drains vmcnt (global_load_lds)

    int kq = (lane >> 4) * 8;
    int lm = lane & 15;
    bf16x8 af[4], bf[4];
#pragma unroll
    for (int mi = 0; mi < 4; ++mi)
      af[mi] = *(const bf16x8*)&As[(wm * 64 + mi * 16 + lm) * 32 + kq];
#pragma unroll
    for (int ni = 0; ni < 4; ++ni)
      bf[ni] = *(const bf16x8*)&Bs[(wn * 64 + ni * 16 + lm) * 32 + kq];
#pragma unroll
    for (int mi = 0; mi < 4; ++mi)
#pragma unroll
      for (int ni = 0; ni < 4; ++ni)
        acc[mi][ni] = __builtin_amdgcn_mfma_f32_16x16x32_bf16(af[mi], bf[ni], acc[mi][ni], 0, 0, 0);
    __syncthreads();
  }

#pragma unroll
  for (int ni = 0; ni < 4; ++ni) {
    int col = n0 + wn * 64 + ni * 16 + (lane & 15);
    float bvv = bias ? loadf(bias + col) : 0.f;
#pragma unroll
    for (int mi = 0; mi < 4; ++mi) {
      int rbase = m0 + wm * 64 + mi * 16 + ((lane >> 4) * 4);
#pragma unroll
      for (int r = 0; r < 4; ++r)
        storef(C + (size_t)(rbase + r) * N + col, acc[mi][ni][r] + bvv);
    }
  }
}

// ---------------- legacy GEMM (B strided-staged) — proj fallback only --------
#define BK 32
#define BSTRIDE 40
#define GEMM_LDS (128 * BK + 128 * BSTRIDE)   // 9216 ushorts

template <typename TB, typename TOUT>
__device__ __forceinline__ void gemm_body(
    const ushortT* __restrict__ A, const TB* __restrict__ Bm,
    const TB* __restrict__ bias, TOUT* __restrict__ C, ushortT* smem)
{
  const int K = 1024, N = 1024;
  ushortT* As = smem;
  ushortT* Bs = smem + 128 * BK;
  int m0 = blockIdx.x * 128;
  int n0 = blockIdx.y * 128;
  int t = threadIdx.x;
  int lane = t & 63;
  int w = t >> 6;
  int wm = w >> 1, wn = w & 1;

  f32x4 acc[4][4] = {};

  const ushortT* a_src0 = A + (size_t)(m0 + (t >> 2)) * K + (t & 3) * 8;
  const ushortT* a_src1 = a_src0 + (size_t)64 * K;
  ushortT* a_dst0 = &As[(16 * w) * BK];
  ushortT* a_dst1 = &As[(64 + 16 * w) * BK];

  int cB = t & 127, r0 = (t >> 7) * 16;
  const TB* Bp0 = Bm + (size_t)r0 * N + n0 + cB;

  TB breg[16];
#pragma unroll
  for (int j = 0; j < 16; ++j) breg[j] = Bp0[(size_t)j * N];

  for (int kt = 0; kt < K; kt += BK) {
    gload16(a_src0 + kt, a_dst0);
    gload16(a_src1 + kt, a_dst1);
    {
      unsigned int* bd = (unsigned int*)&Bs[cB * BSTRIDE + r0];
#pragma unroll
      for (int j = 0; j < 8; ++j) {
        unsigned int lo = tob(breg[2 * j]);
        unsigned int hi = tob(breg[2 * j + 1]);
        bd[j] = lo | (hi << 16);
      }
    }
    __syncthreads();

    if (kt + BK < K) {
      const TB* bp = Bp0 + (size_t)(kt + BK) * N;
#pragma unroll
      for (int j = 0; j < 16; ++j) breg[j] = bp[(size_t)j * N];
    }

    int kq = (lane >> 4) * 8;
    int lm = lane & 15;
    bf16x8 af[4], bf[4];
#pragma unroll
    for (int mi = 0; mi < 4; ++mi)
      af[mi] = *(const bf16x8*)&As[(wm * 64 + mi * 16 + lm) * BK + kq];
#pragma unroll
    for (int ni = 0; ni < 4; ++ni)
      bf[ni] = *(const bf16x8*)&Bs[(wn * 64 + ni * 16 + lm) * BSTRIDE + kq];
#pragma unroll
    for (int mi = 0; mi < 4; ++mi)
#pragma unroll
      for (int ni = 0; ni < 4; ++ni)
        acc[mi][ni] = __builtin_amdgcn_mfma_f32_16x16x32_bf16(af[mi], bf[ni], acc[mi][ni], 0, 0, 0);
    __syncthreads();
  }

#pragma unroll
  for (int ni = 0; ni < 4; ++ni) {
    int col = n0 + wn * 64 + ni * 16 + (lane & 15);
    float bvv = bias ? loadf(bias + col) : 0.f;
#pragma unroll
    for (int mi = 0; mi < 4; ++mi) {
      int rbase = m0 + wm * 64 + mi * 16 + ((lane >> 4) * 4);
#pragma unroll
      for (int r = 0; r < 4; ++r)
        storef(C + (size_t)(rbase + r) * N + col, acc[mi][ni][r] + bvv);
    }
  }
}

// ---------------- MFMA flash attention body, causal, LOAD-BALANCED -----------
// 512 thr / 8 waves; wave w owns 16 q-rows. Block handles q-tile PAIR
// (x, 15-x): exactly 34 key-tile iterations regardless of x.
// Q is ALWAYS bf16 (parked by qkv); K/V native dtype.
#define KSTR 72
#define ATTN_LDS (2 * 64 * KSTR + 8 * 16 * KSTR)   // 18432 ushorts = 36864 B

template <typename TKV>
__device__ __forceinline__ void attn_body(
    const ushortT* __restrict__ Q, const TKV* __restrict__ Kh,
    const TKV* __restrict__ Vh, ushortT* __restrict__ O, ushortT* smem,
    int x, int h, int b)
{
  ushortT* Ks = smem;                 // [key][dim]   9.2 KB
  ushortT* Vs = smem + 64 * KSTR;     // [dim][key]   9.2 KB
  ushortT* Ps = smem + 2 * 64 * KSTR; // per-wave P  18.4 KB

  const int t = threadIdx.x, w = t >> 6, lane = t & 63;
  const int l15 = lane & 15, quad = lane >> 4;

  bf16x8 onesf;
  {
    ushortT u[8];
#pragma unroll
    for (int j = 0; j < 8; ++j) u[j] = 0x3F80;  // bf16 1.0
    onesf = *(bf16x8*)u;
  }

  const TKV* kb = Kh + (size_t)(b * S_) * D_ + h * DH_;
  const TKV* vb = Vh + (size_t)(b * S_) * D_ + h * DH_;
  ushortT* Pw = Ps + w * (16 * KSTR);

  const int krow = t >> 3, kc = t & 7;   // K staging: row 0..63, chunk 0..7
  const int vk = lane;                   // V staging: key row; dims w*8..+7

  for (int pi = 0; pi < 2; ++pi) {
    const int qt = pi ? (15 - x) : x;
    const int q0 = qt * 128;

    bf16x8 qf[2];
    {
      const ushortT* qp = Q + ((size_t)(b * S_) + q0 + w * 16 + l15) * D_ + h * DH_ + quad * 8;
#pragma unroll
      for (int c = 0; c < 2; ++c) {
        ushortT u[8];
        load8b(qp + c * 32, u);
        qf[c] = *(bf16x8*)u;
      }
    }

    f32x4 oac[4];
#pragma unroll
    for (int ni = 0; ni < 4; ++ni) oac[ni] = (f32x4){0.f, 0.f, 0.f, 0.f};
    f32x4 lac = (f32x4){0.f, 0.f, 0.f, 0.f};

    ushortT kr[8], vr[8];
    const int t0max = q0 + 64;

    {
      const TKV* kp = kb + (size_t)krow * D_ + kc * 8;
      load8b(kp, kr);
      const TKV* vp = vb + (size_t)vk * D_ + w * 8;
      load8b(vp, vr);
    }

    for (int t0 = 0; t0 <= t0max; t0 += 64) {
      *(uint4*)&Ks[krow * KSTR + kc * 8] = *(uint4*)kr;
#pragma unroll
      for (int j = 0; j < 8; ++j) Vs[(w * 8 + j) * KSTR + vk] = vr[j];
      __syncthreads();

      if (t0 + 64 <= t0max) {
        const TKV* kp = kb + (size_t)(t0 + 64 + krow) * D_ + kc * 8;
        load8b(kp, kr);
        const TKV* vp = vb + (size_t)(t0 + 64 + vk) * D_ + w * 8;
        load8b(vp, vr);
      }

      // ---- S = Q K^T ----
      f32x4 sac[4];
#pragma unroll
      for (int ni = 0; ni < 4; ++ni) sac[ni] = (f32x4){0.f, 0.f, 0.f, 0.f};
      __builtin_amdgcn_s_setprio(1);
#pragma unroll
      for (int c = 0; c < 2; ++c)
#pragma unroll
        for (int ni = 0; ni < 4; ++ni) {
          bf16x8 bk = *(const bf16x8*)&Ks[(16 * ni + l15) * KSTR + c * 32 + quad * 8];
          sac[ni] = __builtin_amdgcn_mfma_f32_16x16x32_bf16(qf[c], bk, sac[ni], 0, 0, 0);
        }
      __builtin_amdgcn_s_setprio(0);

      // ---- causal mask ----
      if (t0 >= q0) {
        int koff = t0 - q0;
        int rowloc = w * 16 + quad * 4;
#pragma unroll
        for (int ni = 0; ni < 4; ++ni) {
          int kcol = koff + 16 * ni + l15;
#pragma unroll
          for (int r = 0; r < 4; ++r)
            if (kcol > rowloc + r) sac[ni][r] = -1e30f;
        }
      }

      // ---- P = exp(0.125*s) -> per-wave LDS ----
#pragma unroll
      for (int ni = 0; ni < 4; ++ni)
#pragma unroll
        for (int r = 0; r < 4; ++r) {
          float p = __expf(sac[ni][r] * 0.125f);
          Pw[(quad * 4 + r) * KSTR + 16 * ni + l15] = f2b(p);
        }

      // ---- O += P V ; rowsum += P @ ones ----
      __builtin_amdgcn_s_setprio(1);
#pragma unroll
      for (int c = 0; c < 2; ++c) {
        bf16x8 pa = *(const bf16x8*)&Pw[l15 * KSTR + c * 32 + quad * 8];
        lac = __builtin_amdgcn_mfma_f32_16x16x32_bf16(pa, onesf, lac, 0, 0, 0);
#pragma unroll
        for (int ni = 0; ni < 4; ++ni) {
          bf16x8 bv = *(const bf16x8*)&Vs[(16 * ni + l15) * KSTR + c * 32 + quad * 8];
          oac[ni] = __builtin_amdgcn_mfma_f32_16x16x32_bf16(pa, bv, oac[ni], 0, 0, 0);
        }
      }
      __builtin_amdgcn_s_setprio(0);
      __syncthreads();
    }

    // ---- epilogue ----
#pragma unroll
    for (int r = 0; r < 4; ++r) {
      float inv = 1.f / lac[r];
      ushortT* op = O + ((size_t)(b * S_) + q0 + w * 16 + quad * 4 + r) * D_ + h * DH_;
#pragma unroll
      for (int ni = 0; ni < 4; ++ni)
        op[16 * ni + l15] = f2b(oac[ni][r] * inv);
    }
  }
}

// ---------------- merged flag-branching wrappers -----------------------------
// qkv: A bf16 (x / xb), B^T bf16 (pre-transposed into ws). One gemm structure.
__global__ __launch_bounds__(256) void qkv_any(
    const void* x, const ushortT* wt, const void* bq, const void* bv,
    void* outp, const unsigned int* flag) {
  __shared__ __align__(16) ushortT smem[GEMM_BT_LDS];
  int z = blockIdx.z;
  const ushortT* Bt = wt + (size_t)z * 1048576;
  if (*flag == FLAG_BF16) {
    ushortT* o = (ushortT*)outp;
    const ushortT* A = (const ushortT*)x;
    if (z == 0)      gemm_bt<ushortT, ushortT>(A, Bt, (const ushortT*)bq, o, smem);
    else if (z == 1) gemm_bt<ushortT, ushortT>(A, Bt, nullptr, o + (size_t)8388608, smem);
    else             gemm_bt<ushortT, ushortT>(A, Bt, (const ushortT*)bv, o + (size_t)16777216, smem);
  } else {
    float* of = (float*)outp;
    const ushortT* A = (const ushortT*)outp;             // xb, a-region first half
    ushortT* q = (ushortT*)outp + (size_t)8388608;       // a-region, second half
    if (z == 0)      gemm_bt<float, ushortT>(A, Bt, (const float*)bq, q, smem);
    else if (z == 1) gemm_bt<float, float>(A, Bt, nullptr, of + (size_t)8388608, smem);
    else             gemm_bt<float, float>(A, Bt, (const float*)bv, of + (size_t)16777216, smem);
  }
}

// XCD-aware remap: dispatch sends bid -> XCD (bid % 8); remap so the 8
// x-blocks sharing one (b,h) K/V slab land on ONE XCD's L2.
__global__ __launch_bounds__(512, 2) void attn_any(
    void* outp, ushortT* O, const unsigned int* flag) {
  __shared__ __align__(16) ushortT smem[ATTN_LDS];
  int bid = (int)blockIdx.x + 8 * (int)blockIdx.y + 128 * (int)blockIdx.z;
  int lid = (bid & 7) * 64 + (bid >> 3);
  int x = lid & 7, h = (lid >> 3) & 15, b = lid >> 7;
  if (*flag == FLAG_BF16) {
    ushortT* o = (ushortT*)outp;
    attn_body<ushortT>(o, o + (size_t)8388608, o + (size_t)16777216, O, smem, x, h, b);
  } else {
    const ushortT* q = (const ushortT*)outp + (size_t)8388608;
    const float* of = (const float*)outp;
    attn_body<float>(q, of + (size_t)8388608, of + (size_t)16777216, O, smem, x, h, b);
  }
}

__global__ __launch_bounds__(256) void proj_bt(
    const ushortT* A, const ushortT* wct, const void* bc, void* outp,
    const unsigned int* flag) {
  __shared__ __align__(16) ushortT smem[GEMM_BT_LDS];
  if (*flag == FLAG_BF16)
    gemm_bt<ushortT, ushortT>(A, wct, (const ushortT*)bc, (ushortT*)outp, smem);
  else
    gemm_bt<float, float>(A, wct, (const float*)bc, (float*)outp, smem);
}

__global__ __launch_bounds__(256) void proj_legacy(
    const ushortT* A, const void* Wc, const void* bc, void* outp,
    const unsigned int* flag) {
  __shared__ __align__(16) ushortT smem[GEMM_LDS];
  if (*flag == FLAG_BF16)
    gemm_body<ushortT, ushortT>(A, (const ushortT*)Wc, (const ushortT*)bc, (ushortT*)outp, smem);
  else
    gemm_body<float, float>(A, (const float*)Wc, (const float*)bc, (float*)outp, smem);
}

// -----------------------------------------------------------------------------
// ws layout: [0..256) flag; [256..256+16.8M) attn output O (bf16) — during
// qkv this region is DEAD, so Wq^T/Wk^T/Wv^T (bf16, 2MB each) are staged
// there and consumed by qkv before attn overwrites it.
// [256+16.8M .. +2MB) Wc^T iff ws_size permits (else legacy proj).
// f32 d_out a-region: [0..16.78M) xb; [16.78..33.55M) q (bf16).
extern "C" void kernel_launch(void* const* d_in, const int* in_sizes, int n_in,
                              void* d_out, int out_size, void* d_ws, size_t ws_size,
                              hipStream_t stream) {
  (void)in_sizes; (void)n_in; (void)out_size;

  unsigned int* flagp = (unsigned int*)d_ws;
  ushortT* attn_ws = (ushortT*)((char*)d_ws + 256);
  ushortT* wct_p = (ushortT*)((char*)d_ws + 256 + 16777216);
  bool wct_ok = ws_size >= (size_t)(256 + 16777216 + 2097152);

  detect_dtype<<<1, 64, 0, stream>>>((const unsigned int*)d_in[0], flagp);
  cvt_x_f32<<<2048, 256, 0, stream>>>((const float*)d_in[0], (ushortT*)d_out, flagp);

  dim3 gt(D_ / 64, D_ / 64, wct_ok ? 4 : 3);
  transpose_w<<<gt, 256, 0, stream>>>(d_in[1], d_in[3], d_in[4], d_in[6],
                                      attn_ws, wct_p, flagp);

  dim3 gq(MROWS / 128, D_ / 128, 3);  // (64, 8, 3) fused QKV
  dim3 gp(MROWS / 128, D_ / 128);     // (64, 8)    output proj
  dim3 ga(S_ / 256, H_, B_);          // (8, 16, 4) paired causal q-tiles

  qkv_any<<<gq, 256, 0, stream>>>(d_in[0], attn_ws, d_in[2], d_in[5], d_out, flagp);
  attn_any<<<ga, 512, 0, stream>>>(d_out, attn_ws, flagp);
  if (wct_ok)
    proj_bt<<<gp, 256, 0, stream>>>(attn_ws, wct_p, d_in[7], d_out, flagp);
  else
    proj_legacy<<<gp, 256, 0, stream>>>(attn_ws, d_in[6], d_in[7], d_out, flagp);
}

// Round 7
// 324.742 us; speedup vs baseline: 1.3447x; 1.0298x over previous
//
#include <hip/hip_runtime.h>
#include <stdint.h>

#define B_ 4
#define S_ 2048
#define D_ 1024
#define H_ 16
#define DH_ 64
#define MROWS (B_*S_)   // 8192

typedef unsigned short ushortT;
typedef __attribute__((ext_vector_type(8))) short bf16x8;
typedef __attribute__((ext_vector_type(4))) float f32x4;

#define FLAG_BF16 1u
#define FLAG_F32  2u

__device__ __forceinline__ float b2f(ushortT u) {
  union { unsigned int i; float f; } v; v.i = ((unsigned int)u) << 16; return v.f;
}
__device__ __forceinline__ ushortT f2b(float f) {
  union { float f; unsigned int i; } v; v.f = f;
  unsigned int r = v.i + 0x7fffu + ((v.i >> 16) & 1u);
  return (ushortT)(r >> 16);
}
// packed RNE f32x2 -> bf16x2 (no builtin on gfx950; T12 recipe)
__device__ __forceinline__ unsigned int cvtpk(float lo, float hi) {
  unsigned int r;
  asm("v_cvt_pk_bf16_f32 %0, %1, %2" : "=v"(r) : "v"(lo), "v"(hi));
  return r;
}

// scalar load -> float
__device__ __forceinline__ float loadf(const ushortT* p) { return b2f(*p); }
__device__ __forceinline__ float loadf(const float* p)   { return *p; }
// scalar -> bf16 bits (as uint)
__device__ __forceinline__ unsigned int tob(ushortT u) { return u; }
__device__ __forceinline__ unsigned int tob(float f)   { return f2b(f); }

// 8-wide load -> 8 bf16 ushorts (bf16: pure copy, no VALU)
__device__ __forceinline__ void load8b(const ushortT* p, ushortT* u) {
  *(uint4*)u = *(const uint4*)p;
}
__device__ __forceinline__ void load8b(const float* p, ushortT* u) {
  float4 a = ((const float4*)p)[0], b = ((const float4*)p)[1];
  u[0] = f2b(a.x); u[1] = f2b(a.y); u[2] = f2b(a.z); u[3] = f2b(a.w);
  u[4] = f2b(b.x); u[5] = f2b(b.y); u[6] = f2b(b.z); u[7] = f2b(b.w);
}

// dtype-generic store
__device__ __forceinline__ void storef(ushortT* p, float v) { *p = f2b(v); }
__device__ __forceinline__ void storef(float* p, float v)   { *p = v; }

// async global->LDS, 16 bytes per lane (dest = wave-uniform base + lane*16)
__device__ __forceinline__ void gload16(const ushortT* g, ushortT* l) {
  __builtin_amdgcn_global_load_lds(
      (const __attribute__((address_space(1))) void*)g,
      (__attribute__((address_space(3))) void*)l, 16, 0, 0);
}

// ---------------- dtype probe ------------------------------------------------
__global__ void detect_dtype(const unsigned int* __restrict__ xw,
                             unsigned int* __restrict__ flag) {
  int lane = threadIdx.x;
  int cnt = 0;
  for (int i = lane; i < 2048; i += 64) {
    unsigned int e = (xw[i] >> 7) & 0xFFu;
    cnt += (e >= 0x68u && e <= 0x8Au) ? 1 : 0;
  }
#pragma unroll
  for (int off = 32; off; off >>= 1) cnt += __shfl_down(cnt, off);
  if (lane == 0) *flag = (cnt > 1024) ? FLAG_BF16 : FLAG_F32;
}

// ---------------- x -> bf16 one-time convert (f32 pipeline only) -------------
__global__ __launch_bounds__(256) void cvt_x_f32(
    const float* __restrict__ x, ushortT* __restrict__ xb,
    const unsigned int* __restrict__ flag) {
  if (*flag != FLAG_F32) return;
  const int total = MROWS * D_ / 8;  // 8-elem chunks
  for (int i = blockIdx.x * 256 + threadIdx.x; i < total; i += gridDim.x * 256) {
    float4 a = ((const float4*)x)[2 * i], b = ((const float4*)x)[2 * i + 1];
    ushortT u[8];
    u[0] = f2b(a.x); u[1] = f2b(a.y); u[2] = f2b(a.z); u[3] = f2b(a.w);
    u[4] = f2b(b.x); u[5] = f2b(b.y); u[6] = f2b(b.z); u[7] = f2b(b.w);
    ((uint4*)xb)[i] = *(uint4*)u;
  }
}

// ---------------- W -> W^T bf16 one-time transpose ---------------------------
__global__ __launch_bounds__(256) void transpose_w(
    const void* W0, const void* W1, const void* W2, const void* W3,
    ushortT* dst0, ushortT* dstc, const unsigned int* flag) {
  __shared__ ushortT tile[64][72];
  int z = blockIdx.z;
  const void* W = (z == 0) ? W0 : (z == 1) ? W1 : (z == 2) ? W2 : W3;
  ushortT* dst = (z < 3) ? dst0 + (size_t)z * 1048576 : dstc;
  int n0 = blockIdx.x * 64, k0 = blockIdx.y * 64;
  int t = threadIdx.x;
  bool isb = (*flag == FLAG_BF16);
  for (int s = t; s < 512; s += 256) {
    int kr = s >> 3, nc = (s & 7) * 8;
    ushortT u[8];
    if (isb) load8b((const ushortT*)W + (size_t)(k0 + kr) * D_ + n0 + nc, u);
    else     load8b((const float*)W   + (size_t)(k0 + kr) * D_ + n0 + nc, u);
#pragma unroll
    for (int j = 0; j < 8; ++j) tile[kr][nc + j] = u[j];
  }
  __syncthreads();
  for (int s = t; s < 512; s += 256) {
    int nr = s >> 3, kc = (s & 7) * 8;
    ushortT u[8];
#pragma unroll
    for (int j = 0; j < 8; ++j) u[j] = tile[kc + j][nr];
    *(uint4*)(dst + (size_t)(n0 + nr) * D_ + k0 + kc) = *(uint4*)u;
  }
}

// ---------------- V -> Vt (bf16, transposed, permuted+swizzled) --------------
// Per (b,h): Vt[d][key-positions]. Within each 64-key tile, key s sits at
// position p = ((s&15)<<2)|(s>>4)  (matches P's cvt_pk column order), and the
// 16B chunk of p is XORed with (d&7) (bank swizzle for conflict-free b128
// reads). attn stages rows linearly via global_load_lds; PV read applies the
// same XOR. MFMA k-order is permutation-invariant as long as P and V agree.
__global__ __launch_bounds__(256) void vt_build(
    const void* outp, ushortT* vt_f32, ushortT* vt_b16,
    const unsigned int* flag, int wvt_ok) {
  __shared__ ushortT tile[64][72];
  unsigned int fl = *flag;
  if (fl == FLAG_BF16 && !wvt_ok) return;
  ushortT* vt = (fl == FLAG_F32) ? vt_f32 : vt_b16;
  int tile0 = blockIdx.x * 64, h = blockIdx.y, b = blockIdx.z;
  int t = threadIdx.x;
#pragma unroll
  for (int pass = 0; pass < 2; ++pass) {
    int s = (t >> 3) + pass * 32;
    int d0 = (t & 7) * 8;
    ushortT u[8];
    if (fl == FLAG_F32)
      load8b((const float*)outp + (size_t)16777216 +
             ((size_t)(b * S_) + tile0 + s) * D_ + h * DH_ + d0, u);
    else
      load8b((const ushortT*)outp + (size_t)16777216 +
             ((size_t)(b * S_) + tile0 + s) * D_ + h * DH_ + d0, u);
#pragma unroll
    for (int j = 0; j < 8; ++j) tile[s][d0 + j] = u[j];
  }
  __syncthreads();
  int d = t >> 2;
  int pg = (t & 3) * 16;
  ushortT u[16];
#pragma unroll
  for (int j = 0; j < 16; ++j) {
    int pp = pg + j;                       // stored position
    int p = (((pp >> 3) ^ (d & 7)) << 3) | (pp & 7);  // content position
    int s = ((p & 3) << 4) | (p >> 2);     // original key (local)
    u[j] = tile[s][d];
  }
  ushortT* dst = vt + ((size_t)((b * H_ + h) * DH_) + d) * S_ + tile0 + pg;
  *(uint4*)dst = *(uint4*)&u[0];
  *(uint4*)(dst + 8) = *(uint4*)&u[8];
}

// ---------------- MFMA GEMM, both operands bf16, B pre-transposed ------------
#define GEMM_BT_LDS (2 * 128 * 32)   // 8192 ushorts = 16 KB

template <typename TBIAS, typename TOUT>
__device__ __forceinline__ void gemm_bt(
    const ushortT* __restrict__ A, const ushortT* __restrict__ Bt,
    const TBIAS* __restrict__ bias, TOUT* __restrict__ C, ushortT* smem)
{
  const int K = 1024, N = 1024;
  ushortT* As = smem;             // [128][32]
  ushortT* Bs = smem + 128 * 32;  // [128][32]
  int m0 = blockIdx.x * 128;
  int n0 = blockIdx.y * 128;
  int t = threadIdx.x;
  int lane = t & 63;
  int w = t >> 6;
  int wm = w >> 1, wn = w & 1;

  f32x4 acc[4][4] = {};

  const ushortT* a_src0 = A  + (size_t)(m0 + (t >> 2)) * K + (t & 3) * 8;
  const ushortT* a_src1 = a_src0 + (size_t)64 * K;
  const ushortT* b_src0 = Bt + (size_t)(n0 + (t >> 2)) * K + (t & 3) * 8;
  const ushortT* b_src1 = b_src0 + (size_t)64 * K;
  ushortT* a_dst0 = &As[(16 * w) * 32];
  ushortT* a_dst1 = &As[(64 + 16 * w) * 32];
  ushortT* b_dst0 = &Bs[(16 * w) * 32];
  ushortT* b_dst1 = &Bs[(64 + 16 * w) * 32];

  for (int kt = 0; kt < K; kt += 32) {
    gload16(a_src0 + kt, a_dst0);
    gload16(a_src1 + kt, a_dst1);
    gload16(b_src0 + kt, b_dst0);
    gload16(b_src1 + kt, b_dst1);
    __syncthreads();

    int kq = (lane >> 4) * 8;
    int lm = lane & 15;
    bf16x8 af[4], bf[4];
#pragma unroll
    for (int mi = 0; mi < 4; ++mi)
      af[mi] = *(const bf16x8*)&As[(wm * 64 + mi * 16 + lm) * 32 + kq];
#pragma unroll
    for (int ni = 0; ni < 4; ++ni)
      bf[ni] = *(const bf16x8*)&Bs[(wn * 64 + ni * 16 + lm) * 32 + kq];
#pragma unroll
    for (int mi = 0; mi < 4; ++mi)
#pragma unroll
      for (int ni = 0; ni < 4; ++ni)
        acc[mi][ni] = __builtin_amdgcn_mfma_f32_16x16x32_bf16(af[mi], bf[ni], acc[mi][ni], 0, 0, 0);
    __syncthreads();
  }

#pragma unroll
  for (int ni = 0; ni < 4; ++ni) {
    int col = n0 + wn * 64 + ni * 16 + (lane & 15);
    float bvv = bias ? loadf(bias + col) : 0.f;
#pragma unroll
    for (int mi = 0; mi < 4; ++mi) {
      int rbase = m0 + wm * 64 + mi * 16 + ((lane >> 4) * 4);
#pragma unroll
      for (int r = 0; r < 4; ++r)
        storef(C + (size_t)(rbase + r) * N + col, acc[mi][ni][r] + bvv);
    }
  }
}

// ---------------- legacy GEMM (B strided-staged) — proj fallback only --------
#define BK 32
#define BSTRIDE 40
#define GEMM_LDS (128 * BK + 128 * BSTRIDE)

template <typename TB, typename TOUT>
__device__ __forceinline__ void gemm_body(
    const ushortT* __restrict__ A, const TB* __restrict__ Bm,
    const TB* __restrict__ bias, TOUT* __restrict__ C, ushortT* smem)
{
  const int K = 1024, N = 1024;
  ushortT* As = smem;
  ushortT* Bs = smem + 128 * BK;
  int m0 = blockIdx.x * 128;
  int n0 = blockIdx.y * 128;
  int t = threadIdx.x;
  int lane = t & 63;
  int w = t >> 6;
  int wm = w >> 1, wn = w & 1;

  f32x4 acc[4][4] = {};

  const ushortT* a_src0 = A + (size_t)(m0 + (t >> 2)) * K + (t & 3) * 8;
  const ushortT* a_src1 = a_src0 + (size_t)64 * K;
  ushortT* a_dst0 = &As[(16 * w) * BK];
  ushortT* a_dst1 = &As[(64 + 16 * w) * BK];

  int cB = t & 127, r0 = (t >> 7) * 16;
  const TB* Bp0 = Bm + (size_t)r0 * N + n0 + cB;

  TB breg[16];
#pragma unroll
  for (int j = 0; j < 16; ++j) breg[j] = Bp0[(size_t)j * N];

  for (int kt = 0; kt < K; kt += BK) {
    gload16(a_src0 + kt, a_dst0);
    gload16(a_src1 + kt, a_dst1);
    {
      unsigned int* bd = (unsigned int*)&Bs[cB * BSTRIDE + r0];
#pragma unroll
      for (int j = 0; j < 8; ++j) {
        unsigned int lo = tob(breg[2 * j]);
        unsigned int hi = tob(breg[2 * j + 1]);
        bd[j] = lo | (hi << 16);
      }
    }
    __syncthreads();

    if (kt + BK < K) {
      const TB* bp = Bp0 + (size_t)(kt + BK) * N;
#pragma unroll
      for (int j = 0; j < 16; ++j) breg[j] = bp[(size_t)j * N];
    }

    int kq = (lane >> 4) * 8;
    int lm = lane & 15;
    bf16x8 af[4], bf[4];
#pragma unroll
    for (int mi = 0; mi < 4; ++mi)
      af[mi] = *(const bf16x8*)&As[(wm * 64 + mi * 16 + lm) * BK + kq];
#pragma unroll
    for (int ni = 0; ni < 4; ++ni)
      bf[ni] = *(const bf16x8*)&Bs[(wn * 64 + ni * 16 + lm) * BSTRIDE + kq];
#pragma unroll
    for (int mi = 0; mi < 4; ++mi)
#pragma unroll
      for (int ni = 0; ni < 4; ++ni)
        acc[mi][ni] = __builtin_amdgcn_mfma_f32_16x16x32_bf16(af[mi], bf[ni], acc[mi][ni], 0, 0, 0);
    __syncthreads();
  }

#pragma unroll
  for (int ni = 0; ni < 4; ++ni) {
    int col = n0 + wn * 64 + ni * 16 + (lane & 15);
    float bvv = bias ? loadf(bias + col) : 0.f;
#pragma unroll
    for (int mi = 0; mi < 4; ++mi) {
      int rbase = m0 + wm * 64 + mi * 16 + ((lane >> 4) * 4);
#pragma unroll
      for (int r = 0; r < 4; ++r)
        storef(C + (size_t)(rbase + r) * N + col, acc[mi][ni][r] + bvv);
    }
  }
}

// ---------------- MFMA flash attention v2: Vt-DMA + packed-P -----------------
// 512 thr / 8 waves; wave w owns 16 q-rows; q-tile PAIR (x,15-x) per block.
// V: staged by ONE global_load_lds per thread from the permuted+swizzled Vt
//    (double-buffered, no VALU, conflict-free reads).
// P: exp -> 2x v_cvt_pk_bf16_f32 -> one ds_write_b64 per row (columns stored
//    in position order p = l15*4 + ni, matching Vt's permutation).
#define PSTR 72
#define ATTN2_LDS (64 * 72 + 2 * 64 * 64 + 8 * 16 * PSTR)  // 22016 ush = 43 KB

template <typename TK>
__device__ __forceinline__ void attn_body2(
    const ushortT* __restrict__ Q, const TK* __restrict__ Kh,
    const ushortT* __restrict__ Vt, ushortT* __restrict__ O, ushortT* smem,
    int x, int h, int b)
{
  ushortT* Ks = smem;                      // [64 keys][72]
  ushortT* Vs = smem + 64 * 72;            // 2 x [64 dims][64 positions]
  ushortT* Ps = smem + 64 * 72 + 2 * 64 * 64;

  const int t = threadIdx.x, w = t >> 6, lane = t & 63;
  const int l15 = lane & 15, quad = lane >> 4;

  bf16x8 onesf;
  {
    ushortT u[8];
#pragma unroll
    for (int j = 0; j < 8; ++j) u[j] = 0x3F80;  // bf16 1.0
    onesf = *(bf16x8*)u;
  }

  const TK* kb = Kh + (size_t)(b * S_) * D_ + h * DH_;
  const ushortT* vtb = Vt + (size_t)((b * H_ + h) * DH_) * S_;
  ushortT* Pw = Ps + w * (16 * PSTR);

  const int krow = t >> 3, kc = t & 7;     // staging row 0..63, chunk 0..7
  const ushortT* vsrc0 = vtb + (size_t)krow * S_ + kc * 8;

  int cur = 0;
  for (int pi = 0; pi < 2; ++pi) {
    const int qt = pi ? (15 - x) : x;
    const int q0 = qt * 128;

    bf16x8 qf[2];
    {
      const ushortT* qp = Q + ((size_t)(b * S_) + q0 + w * 16 + l15) * D_ + h * DH_ + quad * 8;
#pragma unroll
      for (int c = 0; c < 2; ++c) {
        ushortT u[8];
        load8b(qp + c * 32, u);
        qf[c] = *(bf16x8*)u;
      }
    }

    f32x4 oac[4];
#pragma unroll
    for (int ni = 0; ni < 4; ++ni) oac[ni] = (f32x4){0.f, 0.f, 0.f, 0.f};
    f32x4 lac = (f32x4){0.f, 0.f, 0.f, 0.f};

    ushortT kr[8];
    const int t0max = q0 + 64;

    // prologue: V tile0 -> Vs[cur] via DMA; K tile0 -> regs
    gload16(vsrc0, &Vs[cur * 4096 + w * 512]);
    {
      const TK* kp = kb + (size_t)krow * D_ + kc * 8;
      load8b(kp, kr);
    }

    for (int t0 = 0; t0 <= t0max; t0 += 64) {
      *(uint4*)&Ks[krow * 72 + kc * 8] = *(uint4*)kr;
      __syncthreads();  // drains V DMA (cur) + makes Ks visible

      // prefetch next tile: V DMA -> other buffer, K -> regs
      if (t0 + 64 <= t0max) {
        gload16(vsrc0 + (t0 + 64), &Vs[(cur ^ 1) * 4096 + w * 512]);
        const TK* kp = kb + (size_t)(t0 + 64 + krow) * D_ + kc * 8;
        load8b(kp, kr);
      }

      // ---- S = Q K^T ----
      f32x4 sac[4];
#pragma unroll
      for (int ni = 0; ni < 4; ++ni) sac[ni] = (f32x4){0.f, 0.f, 0.f, 0.f};
      __builtin_amdgcn_s_setprio(1);
#pragma unroll
      for (int c = 0; c < 2; ++c)
#pragma unroll
        for (int ni = 0; ni < 4; ++ni) {
          bf16x8 bk = *(const bf16x8*)&Ks[(16 * ni + l15) * 72 + c * 32 + quad * 8];
          sac[ni] = __builtin_amdgcn_mfma_f32_16x16x32_bf16(qf[c], bk, sac[ni], 0, 0, 0);
        }
      __builtin_amdgcn_s_setprio(0);

      // ---- causal mask (key space, pre-permutation) ----
      if (t0 >= q0) {
        int koff = t0 - q0;
        int rowloc = w * 16 + quad * 4;
#pragma unroll
        for (int ni = 0; ni < 4; ++ni) {
          int kcol = koff + 16 * ni + l15;
#pragma unroll
          for (int r = 0; r < 4; ++r)
            if (kcol > rowloc + r) sac[ni][r] = -1e30f;
        }
      }

      // ---- P = exp(0.125*s): cvt_pk pairs -> b64 writes, permuted cols ----
      // row (quad*4+r), positions 4*l15..+3 hold keys 16*{0,1,2,3}+l15.
#pragma unroll
      for (int r = 0; r < 4; ++r) {
        float e0 = __expf(sac[0][r] * 0.125f);
        float e1 = __expf(sac[1][r] * 0.125f);
        float e2 = __expf(sac[2][r] * 0.125f);
        float e3 = __expf(sac[3][r] * 0.125f);
        uint2 pr;
        pr.x = cvtpk(e0, e1);
        pr.y = cvtpk(e2, e3);
        *(uint2*)&Pw[(quad * 4 + r) * PSTR + 4 * l15] = pr;
      }

      // ---- O += P V ; rowsum += P @ ones  (position-space k, XOR-swizzled V)
      const ushortT* Vsc = Vs + cur * 4096;
      __builtin_amdgcn_s_setprio(1);
#pragma unroll
      for (int c = 0; c < 2; ++c) {
        bf16x8 pa = *(const bf16x8*)&Pw[l15 * PSTR + c * 32 + quad * 8];
        lac = __builtin_amdgcn_mfma_f32_16x16x32_bf16(pa, onesf, lac, 0, 0, 0);
#pragma unroll
        for (int ni = 0; ni < 4; ++ni) {
          int d = 16 * ni + l15;
          bf16x8 bv = *(const bf16x8*)&Vsc[d * 64 + ((((c << 2) + quad) ^ (d & 7)) << 3)];
          oac[ni] = __builtin_amdgcn_mfma_f32_16x16x32_bf16(pa, bv, oac[ni], 0, 0, 0);
        }
      }
      __builtin_amdgcn_s_setprio(0);
      __syncthreads();  // protect Ks rewrite
      cur ^= 1;
    }

    // ---- epilogue: row = q0 + w*16 + quad*4 + r, dim = 16*ni + l15 ----
#pragma unroll
    for (int r = 0; r < 4; ++r) {
      float inv = 1.f / lac[r];
      ushortT* op = O + ((size_t)(b * S_) + q0 + w * 16 + quad * 4 + r) * D_ + h * DH_;
#pragma unroll
      for (int ni = 0; ni < 4; ++ni)
        op[16 * ni + l15] = f2b(oac[ni][r] * inv);
    }
  }
}

// ---------------- fallback attention (round-6 body) — bf16 && small ws -------
#define KSTR 72
#define ATTN_FB_LDS (2 * 64 * KSTR + 8 * 16 * KSTR)

template <typename TKV>
__device__ __forceinline__ void attn_body_fb(
    const ushortT* __restrict__ Q, const TKV* __restrict__ Kh,
    const TKV* __restrict__ Vh, ushortT* __restrict__ O, ushortT* smem,
    int x, int h, int b)
{
  ushortT* Ks = smem;
  ushortT* Vs = smem + 64 * KSTR;
  ushortT* Ps = smem + 2 * 64 * KSTR;

  const int t = threadIdx.x, w = t >> 6, lane = t & 63;
  const int l15 = lane & 15, quad = lane >> 4;

  bf16x8 onesf;
  {
    ushortT u[8];
#pragma unroll
    for (int j = 0; j < 8; ++j) u[j] = 0x3F80;
    onesf = *(bf16x8*)u;
  }

  const TKV* kb = Kh + (size_t)(b * S_) * D_ + h * DH_;
  const TKV* vb = Vh + (size_t)(b * S_) * D_ + h * DH_;
  ushortT* Pw = Ps + w * (16 * KSTR);

  const int krow = t >> 3, kc = t & 7;
  const int vk = lane;

  for (int pi = 0; pi < 2; ++pi) {
    const int qt = pi ? (15 - x) : x;
    const int q0 = qt * 128;

    bf16x8 qf[2];
    {
      const ushortT* qp = Q + ((size_t)(b * S_) + q0 + w * 16 + l15) * D_ + h * DH_ + quad * 8;
#pragma unroll
      for (int c = 0; c < 2; ++c) {
        ushortT u[8];
        load8b(qp + c * 32, u);
        qf[c] = *(bf16x8*)u;
      }
    }

    f32x4 oac[4];
#pragma unroll
    for (int ni = 0; ni < 4; ++ni) oac[ni] = (f32x4){0.f, 0.f, 0.f, 0.f};
    f32x4 lac = (f32x4){0.f, 0.f, 0.f, 0.f};

    ushortT kr[8], vr[8];
    const int t0max = q0 + 64;

    {
      const TKV* kp = kb + (size_t)krow * D_ + kc * 8;
      load8b(kp, kr);
      const TKV* vp = vb + (size_t)vk * D_ + w * 8;
      load8b(vp, vr);
    }

    for (int t0 = 0; t0 <= t0max; t0 += 64) {
      *(uint4*)&Ks[krow * KSTR + kc * 8] = *(uint4*)kr;
#pragma unroll
      for (int j = 0; j < 8; ++j) Vs[(w * 8 + j) * KSTR + vk] = vr[j];
      __syncthreads();

      if (t0 + 64 <= t0max) {
        const TKV* kp = kb + (size_t)(t0 + 64 + krow) * D_ + kc * 8;
        load8b(kp, kr);
        const TKV* vp = vb + (size_t)(t0 + 64 + vk) * D_ + w * 8;
        load8b(vp, vr);
      }

      f32x4 sac[4];
#pragma unroll
      for (int ni = 0; ni < 4; ++ni) sac[ni] = (f32x4){0.f, 0.f, 0.f, 0.f};
#pragma unroll
      for (int c = 0; c < 2; ++c)
#pragma unroll
        for (int ni = 0; ni < 4; ++ni) {
          bf16x8 bk = *(const bf16x8*)&Ks[(16 * ni + l15) * KSTR + c * 32 + quad * 8];
          sac[ni] = __builtin_amdgcn_mfma_f32_16x16x32_bf16(qf[c], bk, sac[ni], 0, 0, 0);
        }

      if (t0 >= q0) {
        int koff = t0 - q0;
        int rowloc = w * 16 + quad * 4;
#pragma unroll
        for (int ni = 0; ni < 4; ++ni) {
          int kcol = koff + 16 * ni + l15;
#pragma unroll
          for (int r = 0; r < 4; ++r)
            if (kcol > rowloc + r) sac[ni][r] = -1e30f;
        }
      }

#pragma unroll
      for (int ni = 0; ni < 4; ++ni)
#pragma unroll
        for (int r = 0; r < 4; ++r) {
          float p = __expf(sac[ni][r] * 0.125f);
          Pw[(quad * 4 + r) * KSTR + 16 * ni + l15] = f2b(p);
        }

#pragma unroll
      for (int c = 0; c < 2; ++c) {
        bf16x8 pa = *(const bf16x8*)&Pw[l15 * KSTR + c * 32 + quad * 8];
        lac = __builtin_amdgcn_mfma_f32_16x16x32_bf16(pa, onesf, lac, 0, 0, 0);
#pragma unroll
        for (int ni = 0; ni < 4; ++ni) {
          bf16x8 bv = *(const bf16x8*)&Vs[(16 * ni + l15) * KSTR + c * 32 + quad * 8];
          oac[ni] = __builtin_amdgcn_mfma_f32_16x16x32_bf16(pa, bv, oac[ni], 0, 0, 0);
        }
      }
      __syncthreads();
    }

#pragma unroll
    for (int r = 0; r < 4; ++r) {
      float inv = 1.f / lac[r];
      ushortT* op = O + ((size_t)(b * S_) + q0 + w * 16 + quad * 4 + r) * D_ + h * DH_;
#pragma unroll
      for (int ni = 0; ni < 4; ++ni)
        op[16 * ni + l15] = f2b(oac[ni][r] * inv);
    }
  }
}

// ---------------- merged flag-branching wrappers -----------------------------
__global__ __launch_bounds__(256) void qkv_any(
    const void* x, const ushortT* wt, const void* bq, const void* bv,
    void* outp, const unsigned int* flag) {
  __shared__ __align__(16) ushortT smem[GEMM_BT_LDS];
  int z = blockIdx.z;
  const ushortT* Bt = wt + (size_t)z * 1048576;
  if (*flag == FLAG_BF16) {
    ushortT* o = (ushortT*)outp;
    const ushortT* A = (const ushortT*)x;
    if (z == 0)      gemm_bt<ushortT, ushortT>(A, Bt, (const ushortT*)bq, o, smem);
    else if (z == 1) gemm_bt<ushortT, ushortT>(A, Bt, nullptr, o + (size_t)8388608, smem);
    else             gemm_bt<ushortT, ushortT>(A, Bt, (const ushortT*)bv, o + (size_t)16777216, smem);
  } else {
    float* of = (float*)outp;
    const ushortT* A = (const ushortT*)outp;             // xb
    ushortT* q = (ushortT*)outp + (size_t)8388608;       // parked bf16 q
    if (z == 0)      gemm_bt<float, ushortT>(A, Bt, (const float*)bq, q, smem);
    else if (z == 1) gemm_bt<float, float>(A, Bt, nullptr, of + (size_t)8388608, smem);
    else             gemm_bt<float, float>(A, Bt, (const float*)bv, of + (size_t)16777216, smem);
  }
}

// XCD-aware remap so the 8 x-blocks sharing one (b,h) K/V slab stay on 1 XCD.
__global__ __launch_bounds__(512, 2) void attn_any(
    void* outp, ushortT* O, const unsigned int* flag,
    const ushortT* vt_b16, int wvt_ok) {
  __shared__ __align__(16) ushortT smem[ATTN2_LDS];
  int bid = (int)blockIdx.x + 8 * (int)blockIdx.y + 128 * (int)blockIdx.z;
  int lid = (bid & 7) * 64 + (bid >> 3);
  int x = lid & 7, h = (lid >> 3) & 15, b = lid >> 7;
  if (*flag == FLAG_BF16) {
    if (!wvt_ok) return;  // attn_fb covers this case
    const ushortT* o = (const ushortT*)outp;
    attn_body2<ushortT>(o, o + (size_t)8388608, vt_b16, O, smem, x, h, b);
  } else {
    const ushortT* q = (const ushortT*)outp + (size_t)8388608;
    const float* of = (const float*)outp;
    attn_body2<float>(q, of + (size_t)8388608, (const ushortT*)outp, O, smem, x, h, b);
  }
}

__global__ __launch_bounds__(512, 2) void attn_fb(
    void* outp, ushortT* O, const unsigned int* flag, int wvt_ok) {
  __shared__ __align__(16) ushortT smem[ATTN_FB_LDS];
  if (!(*flag == FLAG_BF16 && !wvt_ok)) return;
  int bid = (int)blockIdx.x + 8 * (int)blockIdx.y + 128 * (int)blockIdx.z;
  int lid = (bid & 7) * 64 + (bid >> 3);
  int x = lid & 7, h = (lid >> 3) & 15, b = lid >> 7;
  ushortT* o = (ushortT*)outp;
  attn_body_fb<ushortT>(o, o + (size_t)8388608, o + (size_t)16777216, O, smem, x, h, b);
}

__global__ __launch_bounds__(256) void proj_bt(
    const ushortT* A, const ushortT* wct, const void* bc, void* outp,
    const unsigned int* flag) {
  __shared__ __align__(16) ushortT smem[GEMM_BT_LDS];
  if (*flag == FLAG_BF16)
    gemm_bt<ushortT, ushortT>(A, wct, (const ushortT*)bc, (ushortT*)outp, smem);
  else
    gemm_bt<float, float>(A, wct, (const float*)bc, (float*)outp, smem);
}

__global__ __launch_bounds__(256) void proj_legacy(
    const ushortT* A, const void* Wc, const void* bc, void* outp,
    const unsigned int* flag) {
  __shared__ __align__(16) ushortT smem[GEMM_LDS];
  if (*flag == FLAG_BF16)
    gemm_body<ushortT, ushortT>(A, (const ushortT*)Wc, (const ushortT*)bc, (ushortT*)outp, smem);
  else
    gemm_body<float, float>(A, (const float*)Wc, (const float*)bc, (float*)outp, smem);
}

// -----------------------------------------------------------------------------
// ws layout: [0..256) flag; [256..+16.8M) attn O (bf16; doubles as Wq/k/v^T
// staging during qkv); [+16.8M..+2M) Wc^T (guarded); [+18.9M..+16.8M) Vt for
// bf16 path (guarded; f32 Vt reuses the dead xb region of d_out instead).
// f32 d_out a-region: [0..16.78MB) xb -> Vt after qkv; [16.78..33.55MB) q.
extern "C" void kernel_launch(void* const* d_in, const int* in_sizes, int n_in,
                              void* d_out, int out_size, void* d_ws, size_t ws_size,
                              hipStream_t stream) {
  (void)in_sizes; (void)n_in; (void)out_size;

  unsigned int* flagp = (unsigned int*)d_ws;
  ushortT* attn_ws = (ushortT*)((char*)d_ws + 256);
  ushortT* wct_p = (ushortT*)((char*)d_ws + 256 + 16777216);
  ushortT* vtb16_p = (ushortT*)((char*)d_ws + 256 + 16777216 + 2097152);
  bool wct_ok = ws_size >= (size_t)(256 + 16777216 + 2097152);
  int wvt_ok = ws_size >= (size_t)(256 + 16777216 + 2097152 + 16777216) ? 1 : 0;

  detect_dtype<<<1, 64, 0, stream>>>((const unsigned int*)d_in[0], flagp);
  cvt_x_f32<<<2048, 256, 0, stream>>>((const float*)d_in[0], (ushortT*)d_out, flagp);

  dim3 gt(D_ / 64, D_ / 64, wct_ok ? 4 : 3);
  transpose_w<<<gt, 256, 0, stream>>>(d_in[1], d_in[3], d_in[4], d_in[6],
                                      attn_ws, wct_p, flagp);

  dim3 gq(MROWS / 128, D_ / 128, 3);  // (64, 8, 3) fused QKV
  dim3 gv(S_ / 64, H_, B_);           // (32, 16, 4) Vt build
  dim3 gp(MROWS / 128, D_ / 128);     // (64, 8)    output proj
  dim3 ga(S_ / 256, H_, B_);          // (8, 16, 4) paired causal q-tiles

  qkv_any<<<gq, 256, 0, stream>>>(d_in[0], attn_ws, d_in[2], d_in[5], d_out, flagp);
  vt_build<<<gv, 256, 0, stream>>>(d_out, (ushortT*)d_out, vtb16_p, flagp, wvt_ok);
  attn_any<<<ga, 512, 0, stream>>>(d_out, attn_ws, flagp, vtb16_p, wvt_ok);
  attn_fb<<<ga, 512, 0, stream>>>(d_out, attn_ws, flagp, wvt_ok);
  if (wct_ok)
    proj_bt<<<gp, 256, 0, stream>>>(attn_ws, wct_p, d_in[7], d_out, flagp);
  else
    proj_legacy<<<gp, 256, 0, stream>>>(attn_ws, d_in[6], d_in[7], d_out, flagp);
}